// Round 11
// baseline (331.009 us; speedup 1.0000x reference)
//
#include <hip/hip_runtime.h>
#include <stdint.h>

typedef unsigned short u16;
typedef short bf16x8 __attribute__((ext_vector_type(8)));
typedef float f32x4 __attribute__((ext_vector_type(4)));
typedef float f32x16 __attribute__((ext_vector_type(16)));
typedef uint32_t u32x4 __attribute__((ext_vector_type(4)));

#define NB   128
#define SEQ  512
#define EMB  192
#define NTOK (NB * SEQ)   // 65536
#define F1DIM 384
#define ATTW 192          // att row (u16): x1 cols 0..47 & 144..191 at slots 0..95 after outproj; conv(x1[48:144]) at 96..191
#define VTP  520          // V^T row stride (u16)
#define KTS  24           // K row stride (u16)
#define XnS  200          // xn/x1 LDS row stride (u16): 400B, 16B-aligned
#define TNW  192          // tn global row (u16)
#define H1W  384          // h1 global row (u16)
#define W1S  200          // w1 LDS row stride (u16): 400B, 2-way bank alias only
#define W2S  392          // w2 LDS row stride (u16): 784B, 2-way bank alias only

// raw v_exp_f32: scores are pre-scaled into exp2 domain and bounded.
#if __has_builtin(__builtin_amdgcn_exp2f)
#define EXP2F(x) __builtin_amdgcn_exp2f(x)
#else
#define EXP2F(x) exp2f(x)
#endif

__device__ __forceinline__ float bf2f(u16 u) {
  union { uint32_t u; float f; } v; v.u = ((uint32_t)u) << 16; return v.f;
}
// Round 11: f32->bf16 via v_cvt_pk_bf16_f32 (1 VALU op, RTNE — bit-compatible
// with the old manual round-to-nearest-even at ~5 ops).
__device__ __forceinline__ u16 f2bf(float f) {
  uint32_t r;
  asm("v_cvt_pk_bf16_f32 %0, %1, %1" : "=v"(r) : "v"(f));
  return (u16)r;
}
__device__ __forceinline__ uint32_t pack2bf(float a, float b) {
  uint32_t r;
  asm("v_cvt_pk_bf16_f32 %0, %1, %2" : "=v"(r) : "v"(a), "v"(b));
  return r;
}

// ---------------- pack all weights (one launch) ----------------------------
__global__ __launch_bounds__(256) void pack_kernel(const float* __restrict__ w1,
    const float* __restrict__ w2, const float* __restrict__ wqa,
    const float* __restrict__ wqg, const float* __restrict__ woa,
    const float* __restrict__ wog, u16* __restrict__ w1b, u16* __restrict__ w2b,
    u16* __restrict__ wqp, u16* __restrict__ wop) {
  int idx = (int)blockIdx.x * 256 + (int)threadIdx.x;
  if (idx < 73728) {
    w1b[idx] = f2bf(w1[idx]);
  } else if (idx < 147456) {
    w2b[idx - 73728] = f2bf(w2[idx - 73728]);
  } else if (idx < 165888) {
    int i = idx - 147456;
    int row = i >> 6, k = i & 63;
    float v = 0.0f;
    if (k < 48) v = (row < 144) ? wqa[row * 48 + k] : wqg[(row - 144) * 48 + k];
    wqp[i] = f2bf(v);
  } else if (idx < 172032) {
    int i = idx - 165888;
    int row = i >> 6, k = i & 63;
    float v = 0.0f;
    if (k < 48) v = (row < 48) ? woa[row * 48 + k] : wog[(row - 48) * 48 + k];
    wop[i] = f2bf(v);
  }
}

// ---------------- fused LN1 + QKV-proj (MFMA) + conv -----------------------
// Round 11: MFMA split into two 9-col-tile passes (acc[9]=36 VGPR vs
// acc[18]=72) — VGPR 124 capped residency at 4 waves/SIMD while LDS allows
// 6 blocks/CU; target <=90 VGPR -> 24 waves/CU. Weight fragments re-read per
// pass are L2-hot (36KB table). Pass 0 = acc branch (cols 0..143, af from
// xn[0..64)), pass 1 = gyro branch (cols 144..287, af from xn[96..160)).
__global__ __launch_bounds__(256) void ln1_qkv_conv_kernel(
    const float* __restrict__ x, const float* __restrict__ g,
    const float* __restrict__ b, const u16* __restrict__ wq,
    const float* __restrict__ bacc, const float* __restrict__ bgyr,
    const float* __restrict__ cw, u16* __restrict__ qkv,
    u16* __restrict__ att) {
  __shared__ u16 Xn[64 * XnS];
  int bm = (int)blockIdx.x * 64;
  int tid = threadIdx.x;
  int trow = tid >> 2, part = tid & 3;
  int tok = bm + trow;
  const float* xr = x + (size_t)tok * EMB + part * 48;
  float vals[48];
#pragma unroll
  for (int j = 0; j < 48; j += 4) {
    float4 v = *(const float4*)(xr + j);
    vals[j] = v.x; vals[j + 1] = v.y; vals[j + 2] = v.z; vals[j + 3] = v.w;
  }
  float s = 0.0f, s2 = 0.0f;
#pragma unroll
  for (int j = 0; j < 48; j++) { s += vals[j]; s2 += vals[j] * vals[j]; }
  s += __shfl_xor(s, 1); s2 += __shfl_xor(s2, 1);
  s += __shfl_xor(s, 2); s2 += __shfl_xor(s2, 2);
  float mean = s * (1.0f / EMB);
  float var  = s2 * (1.0f / EMB) - mean * mean;
  float rs   = rsqrtf(var + 1e-6f);
  {
    u16* xnrow = Xn + trow * XnS + part * 48;
    const float* gp = g + part * 48;
    const float* bp = b + part * 48;
#pragma unroll
    for (int j = 0; j < 48; j += 2) {
      uint32_t w = pack2bf((vals[j] - mean) * rs * gp[j] + bp[j],
                           (vals[j + 1] - mean) * rs * gp[j + 1] + bp[j + 1]);
      *(uint32_t*)(xnrow + j) = w;
    }
  }
  __syncthreads();
  int wid = tid >> 6, lane = tid & 63;
  int l15 = lane & 15, quad = lane >> 4;
  const u16* arow_l = Xn + (wid * 16 + l15) * XnS;
#pragma unroll 1
  for (int half = 0; half < 2; half++) {
    int abase = half * 96;
    const float* bias_p = half ? bgyr : bacc;
    f32x4 acc[9] = {};
#pragma unroll
    for (int ks = 0; ks < 2; ks++) {
      int kk = ks * 32;
      bf16x8 af = *(const bf16x8*)(arow_l + abase + kk + quad * 8);
#pragma unroll
      for (int s = 0; s < 9; s++) {
        int st = half * 9 + s;
        bf16x8 bf = *(const bf16x8*)(wq + (size_t)(st * 16 + l15) * 64 + kk + quad * 8);
        acc[s] = __builtin_amdgcn_mfma_f32_16x16x32_bf16(af, bf, acc[s], 0, 0, 0);
      }
    }
#pragma unroll
    for (int s = 0; s < 9; s++) {
      int cc = s * 16 + l15;              // 0..143 within branch
      int col = half * 144 + cc;
      float bias = bias_p[cc];
      float qs = (cc < 48) ? 0.36067376022f : 1.0f;  // 0.25*log2(e): exp2-domain scores
#pragma unroll
      for (int r = 0; r < 4; r++) {
        int orow = bm + wid * 16 + quad * 4 + r;
        qkv[(size_t)orow * 288 + col] = f2bf((acc[s][r] + bias) * qs);
      }
    }
  }
  {
    int wr = trow & 3;
    float w15[15];
#pragma unroll
    for (int k = 0; k < 15; k++) w15[k] = cw[wr * 15 + k];
    float win[38];
    int base = part * 24 - 7;
#pragma unroll
    for (int i = 0; i < 38; i++) {
      int p = base + i;
      win[i] = (p >= 0 && p < 96) ? bf2f(Xn[trow * XnS + 48 + p]) : 0.0f;
    }
    const float* xres = x + (size_t)tok * EMB + 48 + part * 24;
    u16* orow = att + (size_t)tok * ATTW + 96 + part * 24;
#pragma unroll
    for (int c = 0; c < 24; c += 4) {
      float4 r4 = *(const float4*)(xres + c);
      float o[4];
#pragma unroll
      for (int u = 0; u < 4; u++) {
        float sc = 0.0f;
#pragma unroll
        for (int k = 0; k < 15; k++) sc += win[c + u + k] * w15[k];
        o[u] = sc;
      }
      *(uint32_t*)(orow + c)     = pack2bf(o[0] + r4.x, o[1] + r4.y);
      *(uint32_t*)(orow + c + 2) = pack2bf(o[2] + r4.z, o[3] + r4.w);
    }
  }
}

// ---------------- MFMA flash attention, max-free exp2 softmax --------------
// 512 thr / 8 waves (2 q-tiles each). permlane32_swap for the cross-half
// P exchange; raw v_exp_f32 via EXP2F.
__global__ __launch_bounds__(512) void attn_kernel(const u16* __restrict__ qkv,
                                                   u16* __restrict__ att) {
  __shared__ u16 Kt[SEQ * KTS];
  __shared__ u16 Vt[17 * VTP];
  int bid = blockIdx.x;
  int hh  = bid % 3;
  int brb = (bid / 3) & 1;
  int b   = bid / 6;
  int tid = threadIdx.x;
  size_t tokbase = (size_t)b * SEQ;
  int qoff = brb * 144 + hh * 16;
  int koff = qoff + 48;
  int voff = qoff + 96;
  {
    int r = tid;  // 512 threads cover SEQ exactly
    const u16* src = qkv + (tokbase + r) * 288;
    *(uint4*)(Kt + r * KTS)     = *(const uint4*)(src + koff);
    *(uint4*)(Kt + r * KTS + 8) = *(const uint4*)(src + koff + 8);
    u16 tmp[16];
    *(uint4*)(tmp)     = *(const uint4*)(src + voff);
    *(uint4*)(tmp + 8) = *(const uint4*)(src + voff + 8);
#pragma unroll
    for (int j = 0; j < 16; j++) Vt[j * VTP + r] = tmp[j];
    Vt[16 * VTP + r] = 0x3F80;  // ones row -> l from the PV MFMA
  }
  __syncthreads();
  int wave = tid >> 6, lane = tid & 63;
  int q31 = lane & 31, h = lane >> 5;
  int dcl = (q31 < 16) ? q31 : 16;
#pragma unroll 1
  for (int qi = 0; qi < 2; qi++) {
    int qrow = (wave * 2 + qi) * 32 + q31;
    bf16x8 qfrag = *(const bf16x8*)(qkv + (tokbase + qrow) * 288 + qoff + h * 8);
    f32x16 Ot = {};
#pragma unroll 2
    for (int kt = 0; kt < 16; kt++) {
      bf16x8 kfrag = *(const bf16x8*)(Kt + (kt * 32 + q31) * KTS + h * 8);
      f32x16 zc = {};
      f32x16 S = __builtin_amdgcn_mfma_f32_32x32x16_bf16(kfrag, qfrag, zc, 0, 0, 0);
      uint32_t pk[8];
#pragma unroll
      for (int i = 0; i < 8; i++) {
        union { float f; uint32_t u; } a0, a1;
        a0.f = EXP2F(S[2 * i]);
        a1.f = EXP2F(S[2 * i + 1]);
        pk[i] = __builtin_amdgcn_perm(a1.u, a0.u, 0x07060302u);
      }
      // permlane32_swap(a,b): a' = {a.lo | b.lo}, b' = {a.hi | b.hi}
      uint32_t s0a = pk[0], s0b = pk[2];
      uint32_t s1a = pk[1], s1b = pk[3];
      uint32_t s2a = pk[4], s2b = pk[6];
      uint32_t s3a = pk[5], s3b = pk[7];
      asm("v_permlane32_swap_b32 %0, %1" : "+v"(s0a), "+v"(s0b));
      asm("v_permlane32_swap_b32 %0, %1" : "+v"(s1a), "+v"(s1b));
      asm("v_permlane32_swap_b32 %0, %1" : "+v"(s2a), "+v"(s2b));
      asm("v_permlane32_swap_b32 %0, %1" : "+v"(s3a), "+v"(s3b));
      u32x4 t1 = { s0a, s1a, s0b, s1b };
      u32x4 t2 = { s2a, s3a, s2b, s3b };
      bf16x8 pb1 = __builtin_bit_cast(bf16x8, t1);
      bf16x8 pb2 = __builtin_bit_cast(bf16x8, t2);
      bf16x8 av1 = *(const bf16x8*)(Vt + dcl * VTP + kt * 32 + h * 8);
      bf16x8 av2 = *(const bf16x8*)(Vt + dcl * VTP + kt * 32 + 16 + h * 8);
      Ot = __builtin_amdgcn_mfma_f32_32x32x16_bf16(av1, pb1, Ot, 0, 0, 0);
      Ot = __builtin_amdgcn_mfma_f32_32x32x16_bf16(av2, pb2, Ot, 0, 0, 0);
    }
    float inv = 1.0f / Ot[8];
    u16* orow = att + (tokbase + qrow) * ATTW + brb * 48 + hh * 16 + 4 * h;
    uint2 st0 = { pack2bf(Ot[0] * inv, Ot[1] * inv),
                  pack2bf(Ot[2] * inv, Ot[3] * inv) };
    uint2 st1 = { pack2bf(Ot[4] * inv, Ot[5] * inv),
                  pack2bf(Ot[6] * inv, Ot[7] * inv) };
    *(uint2*)(orow)     = st0;
    *(uint2*)(orow + 8) = st1;
  }
}

// ---------------- out-proj + residual + LN2 -> tn --------------------------
__global__ __launch_bounds__(256) void outproj_ln2_kernel(
    u16* __restrict__ att, const u16* __restrict__ wo,
    const float* __restrict__ boacc, const float* __restrict__ bogyr,
    const float* __restrict__ x, const float* __restrict__ g2,
    const float* __restrict__ b2v, u16* __restrict__ tn) {
  __shared__ u16 X1[64 * XnS];
  int bm = (int)blockIdx.x * 64;
  int tid = threadIdx.x;
  int wid = tid >> 6, lane = tid & 63;
  int l15 = lane & 15, quad = lane >> 4;
  if (wid < 2) {
    bf16x8 wf[2][3];
#pragma unroll
    for (int s = 0; s < 3; s++) {
      int st = wid * 3 + s;
#pragma unroll
      for (int ks = 0; ks < 2; ks++)
        wf[ks][s] = *(const bf16x8*)(wo + (size_t)(st * 16 + l15) * 64 + ks * 32 + quad * 8);
    }
    f32x4 acc[4][3] = {};
#pragma unroll
    for (int m = 0; m < 4; m++) {
      const u16* ar = att + (size_t)(bm + m * 16 + l15) * ATTW + (wid ? 48 : 0);
#pragma unroll
      for (int ks = 0; ks < 2; ks++) {
        bf16x8 af = *(const bf16x8*)(ar + ks * 32 + quad * 8);
#pragma unroll
        for (int s = 0; s < 3; s++)
          acc[m][s] = __builtin_amdgcn_mfma_f32_16x16x32_bf16(af, wf[ks][s], acc[m][s], 0, 0, 0);
      }
    }
#pragma unroll
    for (int s = 0; s < 3; s++) {
      int col = (wid * 3 + s) * 16 + l15;          // 0..95 (att slot)
      float bias = (col < 48) ? boacc[col] : bogyr[col - 48];
      int oc = (col < 48) ? col : col + 96;        // x1 column
#pragma unroll
      for (int m = 0; m < 4; m++) {
#pragma unroll
        for (int r = 0; r < 4; r++) {
          int lrow = m * 16 + quad * 4 + r;
          float v = acc[m][s][r] + bias + x[(size_t)(bm + lrow) * EMB + oc];
          u16 bv = f2bf(v);
          X1[lrow * XnS + oc] = bv;
          att[(size_t)(bm + lrow) * ATTW + col] = bv;
        }
      }
    }
  } else {
    int trow = (wid - 2) * 32 + (lane >> 1);
    int half = lane & 1;
    const u16* src = att + (size_t)(bm + trow) * ATTW + 96 + half * 48;
    u16* dst = X1 + trow * XnS + 48 + half * 48;
#pragma unroll
    for (int j = 0; j < 48; j += 8)
      *(uint4*)(dst + j) = *(const uint4*)(src + j);
  }
  __syncthreads();
  // LN2: 4 threads/token, 48 cols each
  {
    int trow = tid >> 2, part = tid & 3;
    const u16* xl = X1 + trow * XnS + part * 48;
    float vals[48];
#pragma unroll
    for (int j = 0; j < 48; j += 8) {
      u16 raw[8];
      *(uint4*)raw = *(const uint4*)(xl + j);
#pragma unroll
      for (int u = 0; u < 8; u++) vals[j + u] = bf2f(raw[u]);
    }
    float s = 0.0f, s2 = 0.0f;
#pragma unroll
    for (int j = 0; j < 48; j++) { s += vals[j]; s2 += vals[j] * vals[j]; }
    s += __shfl_xor(s, 1); s2 += __shfl_xor(s2, 1);
    s += __shfl_xor(s, 2); s2 += __shfl_xor(s2, 2);
    float mean = s * (1.0f / EMB);
    float var  = s2 * (1.0f / EMB) - mean * mean;
    float rs   = rsqrtf(var + 1e-6f);
    const float* gp = g2 + part * 48;
    const float* bp = b2v + part * 48;
    u16 obuf[48];
#pragma unroll
    for (int j = 0; j < 48; j += 2) {
      uint32_t w = pack2bf((vals[j] - mean) * rs * gp[j] + bp[j],
                           (vals[j + 1] - mean) * rs * gp[j + 1] + bp[j + 1]);
      *(uint32_t*)(obuf + j) = w;
    }
    u16* tr = tn + (size_t)(bm + trow) * TNW + part * 48;
#pragma unroll
    for (int j = 0; j < 48; j += 8)
      *(uint4*)(tr + j) = *(const uint4*)(obuf + j);
  }
}

// ---------------- FFN gemm1: w1 LDS-stationary, 768 thr = 12 waves ---------
// Full w1 staged per block (grid 256 = 1 block/CU), 12 waves = 2 token-groups
// x 6 col-waves. Each wave: 4 col-tiles, af[4] feeds 16 MFMAs. Zero main-loop
// barriers.
__global__ __launch_bounds__(768) void ffn1_kernel(const u16* __restrict__ tn,
    const u16* __restrict__ w1b, const float* __restrict__ b1,
    u16* __restrict__ h1) {
  __shared__ u16 W1[384 * W1S];  // 153,600 B
  int tid = threadIdx.x;
  for (int i = tid; i < 384 * 24; i += 768) {
    int r = i / 24, sg = i % 24;
    *(uint4*)(W1 + r * W1S + sg * 8) = *(const uint4*)(w1b + r * 192 + sg * 8);
  }
  __syncthreads();
  int wid = tid >> 6, lane = tid & 63;
  int l15 = lane & 15, quad = lane >> 4;
  int tg = (wid >= 6) ? 1 : 0;
  int cw = wid - tg * 6;          // 0..5, owns 4 col-tiles
  int tok0 = (int)blockIdx.x * 256 + tg * 128;
  float bias[4];
#pragma unroll
  for (int s = 0; s < 4; s++) bias[s] = b1[(cw * 4 + s) * 16 + l15];
#pragma unroll 1
  for (int mc = 0; mc < 2; mc++) {
    int tb = tok0 + mc * 64;
    f32x4 acc[4][4] = {};
#pragma unroll
    for (int kk = 0; kk < 192; kk += 32) {
      bf16x8 af[4];
#pragma unroll
      for (int m = 0; m < 4; m++)
        af[m] = *(const bf16x8*)(tn + (size_t)(tb + m * 16 + l15) * TNW + kk + quad * 8);
#pragma unroll
      for (int s = 0; s < 4; s++) {
        bf16x8 bf = *(const bf16x8*)(W1 + (size_t)((cw * 4 + s) * 16 + l15) * W1S + kk + quad * 8);
#pragma unroll
        for (int m = 0; m < 4; m++)
          acc[m][s] = __builtin_amdgcn_mfma_f32_16x16x32_bf16(af[m], bf, acc[m][s], 0, 0, 0);
      }
    }
#pragma unroll
    for (int m = 0; m < 4; m++) {
#pragma unroll
      for (int s = 0; s < 4; s++) {
        int col = (cw * 4 + s) * 16 + l15;
#pragma unroll
        for (int r = 0; r < 4; r++) {
          float v = acc[m][s][r] + bias[s];
          v = v > 0.0f ? v : 0.0f;
          h1[(size_t)(tb + m * 16 + quad * 4 + r) * H1W + col] = f2bf(v);
        }
      }
    }
  }
}

// ---------------- FFN gemm2 + residual: w2 LDS-stationary, 768 thr ---------
// Full w2 per block (grid 256), 12 waves = 2 token-groups x 6 col-waves x
// 2 col-tiles. af[4] feeds 8 MFMAs; zero main-loop barriers.
__global__ __launch_bounds__(768) void ffn2_kernel(const u16* __restrict__ h1,
    const u16* __restrict__ w2b, const float* __restrict__ b2,
    const u16* __restrict__ att, float* __restrict__ out) {
  __shared__ u16 W2[192 * W2S];  // 150,528 B
  int tid = threadIdx.x;
  for (int i = tid; i < 192 * 48; i += 768) {
    int r = i / 48, sg = i % 48;
    *(uint4*)(W2 + r * W2S + sg * 8) = *(const uint4*)(w2b + r * 384 + sg * 8);
  }
  __syncthreads();
  int wid = tid >> 6, lane = tid & 63;
  int l15 = lane & 15, quad = lane >> 4;
  int tg = (wid >= 6) ? 1 : 0;
  int cw = wid - tg * 6;          // 0..5, owns 2 col-tiles
  int tok0 = (int)blockIdx.x * 256 + tg * 128;
  float bias[2];
  int aoff[2];
#pragma unroll
  for (int s = 0; s < 2; s++) {
    int col = (cw * 2 + s) * 16 + l15;
    bias[s] = b2[col];
    aoff[s] = (col < 48) ? col : ((col < 144) ? col + 48 : col - 96);
  }
#pragma unroll 1
  for (int mc = 0; mc < 2; mc++) {
    int tb = tok0 + mc * 64;
    f32x4 acc[4][2] = {};
#pragma unroll
    for (int kk = 0; kk < 384; kk += 32) {
      bf16x8 af[4];
#pragma unroll
      for (int m = 0; m < 4; m++)
        af[m] = *(const bf16x8*)(h1 + (size_t)(tb + m * 16 + l15) * H1W + kk + quad * 8);
#pragma unroll
      for (int s = 0; s < 2; s++) {
        bf16x8 bf = *(const bf16x8*)(W2 + (size_t)((cw * 2 + s) * 16 + l15) * W2S + kk + quad * 8);
#pragma unroll
        for (int m = 0; m < 4; m++)
          acc[m][s] = __builtin_amdgcn_mfma_f32_16x16x32_bf16(af[m], bf, acc[m][s], 0, 0, 0);
      }
    }
#pragma unroll
    for (int m = 0; m < 4; m++) {
#pragma unroll
      for (int s = 0; s < 2; s++) {
        int col = (cw * 2 + s) * 16 + l15;
#pragma unroll
        for (int r = 0; r < 4; r++) {
          int tok = tb + m * 16 + quad * 4 + r;
          float v = acc[m][s][r] + bias[s];
          v = v > 0.0f ? v : 0.0f;
          out[(size_t)tok * EMB + col] = v + bf2f(att[(size_t)tok * ATTW + aoff[s]]);
        }
      }
    }
  }
}

extern "C" void kernel_launch(void* const* d_in, const int* in_sizes, int n_in,
                              void* d_out, int out_size, void* d_ws, size_t ws_size,
                              hipStream_t stream) {
  const float* x         = (const float*)d_in[0];
  const float* ln1_g     = (const float*)d_in[1];
  const float* ln1_b     = (const float*)d_in[2];
  const float* acc_wqkv  = (const float*)d_in[3];
  const float* acc_bqkv  = (const float*)d_in[4];
  const float* acc_wo    = (const float*)d_in[5];
  const float* acc_bo    = (const float*)d_in[6];
  const float* gyro_wqkv = (const float*)d_in[7];
  const float* gyro_bqkv = (const float*)d_in[8];
  const float* gyro_wo   = (const float*)d_in[9];
  const float* gyro_bo   = (const float*)d_in[10];
  const float* conv_w    = (const float*)d_in[11];
  const float* ln2_g     = (const float*)d_in[12];
  const float* ln2_b     = (const float*)d_in[13];
  const float* w1        = (const float*)d_in[14];
  const float* b1        = (const float*)d_in[15];
  const float* w2        = (const float*)d_in[16];
  const float* b2        = (const float*)d_in[17];
  float* out = (float*)d_out;
  char* ws = (char*)d_ws;

  u16* qkvb = (u16*)(ws);                      // [N,288] bf16  37,748,736
  u16* tnb  = (u16*)(ws);                      // [N,192] bf16  25,165,824 (aliases dead qkvb)
  u16* attb = (u16*)(ws + 37748736);           // [N,192] bf16  25,165,824
  u16* w1b  = (u16*)(ws + 62914560);           // 147,456
  u16* w2b  = (u16*)(ws + 63062016);           // 147,456
  u16* wqp  = (u16*)(ws + 63209472);           // 36,864
  u16* wop  = (u16*)(ws + 63246336);           // 12,288
  u16* h1b  = (u16*)(ws + 63258624);           // [N,384] bf16  50,331,648 -> end 113,590,272

  pack_kernel<<<672, 256, 0, stream>>>(w1, w2, acc_wqkv, gyro_wqkv, acc_wo,
                                       gyro_wo, w1b, w2b, wqp, wop);
  ln1_qkv_conv_kernel<<<NTOK / 64, 256, 0, stream>>>(
      x, ln1_g, ln1_b, wqp, acc_bqkv, gyro_bqkv, conv_w, qkvb, attb);
  attn_kernel<<<NB * 6, 512, 0, stream>>>(qkvb, attb);
  outproj_ln2_kernel<<<NTOK / 64, 256, 0, stream>>>(
      attb, wop, acc_bo, gyro_bo, x, ln2_g, ln2_b, tnb);
  ffn1_kernel<<<256, 768, 0, stream>>>(tnb, w1b, b1, h1b);
  ffn2_kernel<<<256, 768, 0, stream>>>(h1b, w2b, b2, attb, out);
}

// Round 12
// 318.410 us; speedup vs baseline: 1.0396x; 1.0396x over previous
//
#include <hip/hip_runtime.h>
#include <stdint.h>

typedef unsigned short u16;
typedef short bf16x8 __attribute__((ext_vector_type(8)));
typedef float f32x4 __attribute__((ext_vector_type(4)));
typedef float f32x16 __attribute__((ext_vector_type(16)));
typedef uint32_t u32x4 __attribute__((ext_vector_type(4)));

#define NB   128
#define SEQ  512
#define EMB  192
#define NTOK (NB * SEQ)   // 65536
#define F1DIM 384
#define ATTW 192          // att row (u16): x1 cols 0..47 & 144..191 at slots 0..95 after outproj; conv(x1[48:144]) at 96..191
#define VTP  520          // V^T row stride (u16)
#define KTS  24           // K row stride (u16)
#define XnS  200          // xn/x1 LDS row stride (u16): 400B, 16B-aligned
#define TNW  192          // tn global row (u16)
#define H1W  384          // h1 global row (u16)
#define W1S  200          // w1 LDS row stride (u16): 400B, 2-way bank alias only
#define W2S  392          // w2 LDS row stride (u16): 784B, 2-way bank alias only

// raw v_exp_f32: scores are pre-scaled into exp2 domain and bounded.
#if __has_builtin(__builtin_amdgcn_exp2f)
#define EXP2F(x) __builtin_amdgcn_exp2f(x)
#else
#define EXP2F(x) exp2f(x)
#endif

__device__ __forceinline__ float bf2f(u16 u) {
  union { uint32_t u; float f; } v; v.u = ((uint32_t)u) << 16; return v.f;
}
// f32->bf16 via v_cvt_pk_bf16_f32 (1 VALU op, RTNE).
__device__ __forceinline__ u16 f2bf(float f) {
  uint32_t r;
  asm("v_cvt_pk_bf16_f32 %0, %1, %1" : "=v"(r) : "v"(f));
  return (u16)r;
}
__device__ __forceinline__ uint32_t pack2bf(float a, float b) {
  uint32_t r;
  asm("v_cvt_pk_bf16_f32 %0, %1, %2" : "=v"(r) : "v"(a), "v"(b));
  return r;
}

// ---------------- pack all weights (one launch) ----------------------------
__global__ __launch_bounds__(256) void pack_kernel(const float* __restrict__ w1,
    const float* __restrict__ w2, const float* __restrict__ wqa,
    const float* __restrict__ wqg, const float* __restrict__ woa,
    const float* __restrict__ wog, u16* __restrict__ w1b, u16* __restrict__ w2b,
    u16* __restrict__ wqp, u16* __restrict__ wop) {
  int idx = (int)blockIdx.x * 256 + (int)threadIdx.x;
  if (idx < 73728) {
    w1b[idx] = f2bf(w1[idx]);
  } else if (idx < 147456) {
    w2b[idx - 73728] = f2bf(w2[idx - 73728]);
  } else if (idx < 165888) {
    int i = idx - 147456;
    int row = i >> 6, k = i & 63;
    float v = 0.0f;
    if (k < 48) v = (row < 144) ? wqa[row * 48 + k] : wqg[(row - 144) * 48 + k];
    wqp[i] = f2bf(v);
  } else if (idx < 172032) {
    int i = idx - 165888;
    int row = i >> 6, k = i & 63;
    float v = 0.0f;
    if (k < 48) v = (row < 48) ? woa[row * 48 + k] : wog[(row - 48) * 48 + k];
    wop[i] = f2bf(v);
  }
}

// ---------------- fused LN1 + QKV-proj (MFMA) + conv -----------------------
// Round 12: 32 tokens/block, grid 2048 (was 64/1024). ln1 was grid-shallow:
// only 4 blocks/CU of total work, measured ~7.5 waves/CU average despite
// 24-wave residency headroom. Doubling grid depth doubles the overlap pool.
// LDS 12.8KB; LN = 8 thr/token (24 cols); MFMA = 4 waves: (m-tile, branch-
// half) each with acc[9]; conv = 8 thr/token (12 cols, 26-elem window).
__global__ __launch_bounds__(256) void ln1_qkv_conv_kernel(
    const float* __restrict__ x, const float* __restrict__ g,
    const float* __restrict__ b, const u16* __restrict__ wq,
    const float* __restrict__ bacc, const float* __restrict__ bgyr,
    const float* __restrict__ cw, u16* __restrict__ qkv,
    u16* __restrict__ att) {
  __shared__ u16 Xn[32 * XnS];
  int bm = (int)blockIdx.x * 32;
  int tid = threadIdx.x;
  int trow = tid >> 3, part = tid & 7;
  int tok = bm + trow;
  const float* xr = x + (size_t)tok * EMB + part * 24;
  float vals[24];
#pragma unroll
  for (int j = 0; j < 24; j += 4) {
    float4 v = *(const float4*)(xr + j);
    vals[j] = v.x; vals[j + 1] = v.y; vals[j + 2] = v.z; vals[j + 3] = v.w;
  }
  float s = 0.0f, s2 = 0.0f;
#pragma unroll
  for (int j = 0; j < 24; j++) { s += vals[j]; s2 += vals[j] * vals[j]; }
  s += __shfl_xor(s, 1); s2 += __shfl_xor(s2, 1);
  s += __shfl_xor(s, 2); s2 += __shfl_xor(s2, 2);
  s += __shfl_xor(s, 4); s2 += __shfl_xor(s2, 4);
  float mean = s * (1.0f / EMB);
  float var  = s2 * (1.0f / EMB) - mean * mean;
  float rs   = rsqrtf(var + 1e-6f);
  {
    u16* xnrow = Xn + trow * XnS + part * 24;
    const float* gp = g + part * 24;
    const float* bp = b + part * 24;
#pragma unroll
    for (int j = 0; j < 24; j += 2) {
      uint32_t w = pack2bf((vals[j] - mean) * rs * gp[j] + bp[j],
                           (vals[j + 1] - mean) * rs * gp[j + 1] + bp[j + 1]);
      *(uint32_t*)(xnrow + j) = w;
    }
  }
  __syncthreads();
  int wid = tid >> 6, lane = tid & 63;
  int l15 = lane & 15, quad = lane >> 4;
  {
    int mt = wid & 1, half = wid >> 1;
    const u16* arow_l = Xn + (mt * 16 + l15) * XnS + half * 96;
    const float* bias_p = half ? bgyr : bacc;
    f32x4 acc[9] = {};
#pragma unroll
    for (int ks = 0; ks < 2; ks++) {
      int kk = ks * 32;
      bf16x8 af = *(const bf16x8*)(arow_l + kk + quad * 8);
#pragma unroll
      for (int s9 = 0; s9 < 9; s9++) {
        int st = half * 9 + s9;
        bf16x8 bf = *(const bf16x8*)(wq + (size_t)(st * 16 + l15) * 64 + kk + quad * 8);
        acc[s9] = __builtin_amdgcn_mfma_f32_16x16x32_bf16(af, bf, acc[s9], 0, 0, 0);
      }
    }
#pragma unroll
    for (int s9 = 0; s9 < 9; s9++) {
      int cc = s9 * 16 + l15;             // 0..143 within branch
      int col = half * 144 + cc;
      float bias = bias_p[cc];
      float qs = (cc < 48) ? 0.36067376022f : 1.0f;  // 0.25*log2(e): exp2-domain scores
#pragma unroll
      for (int r = 0; r < 4; r++) {
        int orow = bm + mt * 16 + quad * 4 + r;
        qkv[(size_t)orow * 288 + col] = f2bf((acc[s9][r] + bias) * qs);
      }
    }
  }
  {
    int wr = trow & 3;
    float w15[15];
#pragma unroll
    for (int k = 0; k < 15; k++) w15[k] = cw[wr * 15 + k];
    float win[26];
    int base = part * 12 - 7;
#pragma unroll
    for (int i = 0; i < 26; i++) {
      int p = base + i;
      win[i] = (p >= 0 && p < 96) ? bf2f(Xn[trow * XnS + 48 + p]) : 0.0f;
    }
    const float* xres = x + (size_t)tok * EMB + 48 + part * 12;
    u16* orow = att + (size_t)tok * ATTW + 96 + part * 12;
#pragma unroll
    for (int c = 0; c < 12; c += 4) {
      float4 r4 = *(const float4*)(xres + c);
      float o[4];
#pragma unroll
      for (int u = 0; u < 4; u++) {
        float sc = 0.0f;
#pragma unroll
        for (int k = 0; k < 15; k++) sc += win[c + u + k] * w15[k];
        o[u] = sc;
      }
      *(uint32_t*)(orow + c)     = pack2bf(o[0] + r4.x, o[1] + r4.y);
      *(uint32_t*)(orow + c + 2) = pack2bf(o[2] + r4.z, o[3] + r4.w);
    }
  }
}

// ---------------- MFMA flash attention, max-free exp2 softmax --------------
// 512 thr / 8 waves (2 q-tiles each). permlane32_swap for the cross-half
// P exchange; raw v_exp_f32 via EXP2F.
__global__ __launch_bounds__(512) void attn_kernel(const u16* __restrict__ qkv,
                                                   u16* __restrict__ att) {
  __shared__ u16 Kt[SEQ * KTS];
  __shared__ u16 Vt[17 * VTP];
  int bid = blockIdx.x;
  int hh  = bid % 3;
  int brb = (bid / 3) & 1;
  int b   = bid / 6;
  int tid = threadIdx.x;
  size_t tokbase = (size_t)b * SEQ;
  int qoff = brb * 144 + hh * 16;
  int koff = qoff + 48;
  int voff = qoff + 96;
  {
    int r = tid;  // 512 threads cover SEQ exactly
    const u16* src = qkv + (tokbase + r) * 288;
    *(uint4*)(Kt + r * KTS)     = *(const uint4*)(src + koff);
    *(uint4*)(Kt + r * KTS + 8) = *(const uint4*)(src + koff + 8);
    u16 tmp[16];
    *(uint4*)(tmp)     = *(const uint4*)(src + voff);
    *(uint4*)(tmp + 8) = *(const uint4*)(src + voff + 8);
#pragma unroll
    for (int j = 0; j < 16; j++) Vt[j * VTP + r] = tmp[j];
    Vt[16 * VTP + r] = 0x3F80;  // ones row -> l from the PV MFMA
  }
  __syncthreads();
  int wave = tid >> 6, lane = tid & 63;
  int q31 = lane & 31, h = lane >> 5;
  int dcl = (q31 < 16) ? q31 : 16;
#pragma unroll 1
  for (int qi = 0; qi < 2; qi++) {
    int qrow = (wave * 2 + qi) * 32 + q31;
    bf16x8 qfrag = *(const bf16x8*)(qkv + (tokbase + qrow) * 288 + qoff + h * 8);
    f32x16 Ot = {};
#pragma unroll 2
    for (int kt = 0; kt < 16; kt++) {
      bf16x8 kfrag = *(const bf16x8*)(Kt + (kt * 32 + q31) * KTS + h * 8);
      f32x16 zc = {};
      f32x16 S = __builtin_amdgcn_mfma_f32_32x32x16_bf16(kfrag, qfrag, zc, 0, 0, 0);
      uint32_t pk[8];
#pragma unroll
      for (int i = 0; i < 8; i++) {
        union { float f; uint32_t u; } a0, a1;
        a0.f = EXP2F(S[2 * i]);
        a1.f = EXP2F(S[2 * i + 1]);
        pk[i] = __builtin_amdgcn_perm(a1.u, a0.u, 0x07060302u);
      }
      // permlane32_swap(a,b): a' = {a.lo | b.lo}, b' = {a.hi | b.hi}
      uint32_t s0a = pk[0], s0b = pk[2];
      uint32_t s1a = pk[1], s1b = pk[3];
      uint32_t s2a = pk[4], s2b = pk[6];
      uint32_t s3a = pk[5], s3b = pk[7];
      asm("v_permlane32_swap_b32 %0, %1" : "+v"(s0a), "+v"(s0b));
      asm("v_permlane32_swap_b32 %0, %1" : "+v"(s1a), "+v"(s1b));
      asm("v_permlane32_swap_b32 %0, %1" : "+v"(s2a), "+v"(s2b));
      asm("v_permlane32_swap_b32 %0, %1" : "+v"(s3a), "+v"(s3b));
      u32x4 t1 = { s0a, s1a, s0b, s1b };
      u32x4 t2 = { s2a, s3a, s2b, s3b };
      bf16x8 pb1 = __builtin_bit_cast(bf16x8, t1);
      bf16x8 pb2 = __builtin_bit_cast(bf16x8, t2);
      bf16x8 av1 = *(const bf16x8*)(Vt + dcl * VTP + kt * 32 + h * 8);
      bf16x8 av2 = *(const bf16x8*)(Vt + dcl * VTP + kt * 32 + 16 + h * 8);
      Ot = __builtin_amdgcn_mfma_f32_32x32x16_bf16(av1, pb1, Ot, 0, 0, 0);
      Ot = __builtin_amdgcn_mfma_f32_32x32x16_bf16(av2, pb2, Ot, 0, 0, 0);
    }
    float inv = 1.0f / Ot[8];
    u16* orow = att + (tokbase + qrow) * ATTW + brb * 48 + hh * 16 + 4 * h;
    uint2 st0 = { pack2bf(Ot[0] * inv, Ot[1] * inv),
                  pack2bf(Ot[2] * inv, Ot[3] * inv) };
    uint2 st1 = { pack2bf(Ot[4] * inv, Ot[5] * inv),
                  pack2bf(Ot[6] * inv, Ot[7] * inv) };
    *(uint2*)(orow)     = st0;
    *(uint2*)(orow + 8) = st1;
  }
}

// ---------------- out-proj + residual + LN2 -> tn --------------------------
__global__ __launch_bounds__(256) void outproj_ln2_kernel(
    u16* __restrict__ att, const u16* __restrict__ wo,
    const float* __restrict__ boacc, const float* __restrict__ bogyr,
    const float* __restrict__ x, const float* __restrict__ g2,
    const float* __restrict__ b2v, u16* __restrict__ tn) {
  __shared__ u16 X1[64 * XnS];
  int bm = (int)blockIdx.x * 64;
  int tid = threadIdx.x;
  int wid = tid >> 6, lane = tid & 63;
  int l15 = lane & 15, quad = lane >> 4;
  if (wid < 2) {
    bf16x8 wf[2][3];
#pragma unroll
    for (int s = 0; s < 3; s++) {
      int st = wid * 3 + s;
#pragma unroll
      for (int ks = 0; ks < 2; ks++)
        wf[ks][s] = *(const bf16x8*)(wo + (size_t)(st * 16 + l15) * 64 + ks * 32 + quad * 8);
    }
    f32x4 acc[4][3] = {};
#pragma unroll
    for (int m = 0; m < 4; m++) {
      const u16* ar = att + (size_t)(bm + m * 16 + l15) * ATTW + (wid ? 48 : 0);
#pragma unroll
      for (int ks = 0; ks < 2; ks++) {
        bf16x8 af = *(const bf16x8*)(ar + ks * 32 + quad * 8);
#pragma unroll
        for (int s = 0; s < 3; s++)
          acc[m][s] = __builtin_amdgcn_mfma_f32_16x16x32_bf16(af, wf[ks][s], acc[m][s], 0, 0, 0);
      }
    }
#pragma unroll
    for (int s = 0; s < 3; s++) {
      int col = (wid * 3 + s) * 16 + l15;          // 0..95 (att slot)
      float bias = (col < 48) ? boacc[col] : bogyr[col - 48];
      int oc = (col < 48) ? col : col + 96;        // x1 column
#pragma unroll
      for (int m = 0; m < 4; m++) {
#pragma unroll
        for (int r = 0; r < 4; r++) {
          int lrow = m * 16 + quad * 4 + r;
          float v = acc[m][s][r] + bias + x[(size_t)(bm + lrow) * EMB + oc];
          u16 bv = f2bf(v);
          X1[lrow * XnS + oc] = bv;
          att[(size_t)(bm + lrow) * ATTW + col] = bv;
        }
      }
    }
  } else {
    int trow = (wid - 2) * 32 + (lane >> 1);
    int half = lane & 1;
    const u16* src = att + (size_t)(bm + trow) * ATTW + 96 + half * 48;
    u16* dst = X1 + trow * XnS + 48 + half * 48;
#pragma unroll
    for (int j = 0; j < 48; j += 8)
      *(uint4*)(dst + j) = *(const uint4*)(src + j);
  }
  __syncthreads();
  // LN2: 4 threads/token, 48 cols each
  {
    int trow = tid >> 2, part = tid & 3;
    const u16* xl = X1 + trow * XnS + part * 48;
    float vals[48];
#pragma unroll
    for (int j = 0; j < 48; j += 8) {
      u16 raw[8];
      *(uint4*)raw = *(const uint4*)(xl + j);
#pragma unroll
      for (int u = 0; u < 8; u++) vals[j + u] = bf2f(raw[u]);
    }
    float s = 0.0f, s2 = 0.0f;
#pragma unroll
    for (int j = 0; j < 48; j++) { s += vals[j]; s2 += vals[j] * vals[j]; }
    s += __shfl_xor(s, 1); s2 += __shfl_xor(s2, 1);
    s += __shfl_xor(s, 2); s2 += __shfl_xor(s2, 2);
    float mean = s * (1.0f / EMB);
    float var  = s2 * (1.0f / EMB) - mean * mean;
    float rs   = rsqrtf(var + 1e-6f);
    const float* gp = g2 + part * 48;
    const float* bp = b2v + part * 48;
    u16 obuf[48];
#pragma unroll
    for (int j = 0; j < 48; j += 2) {
      uint32_t w = pack2bf((vals[j] - mean) * rs * gp[j] + bp[j],
                           (vals[j + 1] - mean) * rs * gp[j + 1] + bp[j + 1]);
      *(uint32_t*)(obuf + j) = w;
    }
    u16* tr = tn + (size_t)(bm + trow) * TNW + part * 48;
#pragma unroll
    for (int j = 0; j < 48; j += 8)
      *(uint4*)(tr + j) = *(const uint4*)(obuf + j);
  }
}

// ---------------- FFN gemm1: w1 LDS-stationary, 768 thr = 12 waves ---------
// Full w1 staged per block (grid 256 = 1 block/CU), 12 waves = 2 token-groups
// x 6 col-waves. Each wave: 4 col-tiles, af[4] feeds 16 MFMAs. Zero main-loop
// barriers.
__global__ __launch_bounds__(768) void ffn1_kernel(const u16* __restrict__ tn,
    const u16* __restrict__ w1b, const float* __restrict__ b1,
    u16* __restrict__ h1) {
  __shared__ u16 W1[384 * W1S];  // 153,600 B
  int tid = threadIdx.x;
  for (int i = tid; i < 384 * 24; i += 768) {
    int r = i / 24, sg = i % 24;
    *(uint4*)(W1 + r * W1S + sg * 8) = *(const uint4*)(w1b + r * 192 + sg * 8);
  }
  __syncthreads();
  int wid = tid >> 6, lane = tid & 63;
  int l15 = lane & 15, quad = lane >> 4;
  int tg = (wid >= 6) ? 1 : 0;
  int cw = wid - tg * 6;          // 0..5, owns 4 col-tiles
  int tok0 = (int)blockIdx.x * 256 + tg * 128;
  float bias[4];
#pragma unroll
  for (int s = 0; s < 4; s++) bias[s] = b1[(cw * 4 + s) * 16 + l15];
#pragma unroll 1
  for (int mc = 0; mc < 2; mc++) {
    int tb = tok0 + mc * 64;
    f32x4 acc[4][4] = {};
#pragma unroll
    for (int kk = 0; kk < 192; kk += 32) {
      bf16x8 af[4];
#pragma unroll
      for (int m = 0; m < 4; m++)
        af[m] = *(const bf16x8*)(tn + (size_t)(tb + m * 16 + l15) * TNW + kk + quad * 8);
#pragma unroll
      for (int s = 0; s < 4; s++) {
        bf16x8 bf = *(const bf16x8*)(W1 + (size_t)((cw * 4 + s) * 16 + l15) * W1S + kk + quad * 8);
#pragma unroll
        for (int m = 0; m < 4; m++)
          acc[m][s] = __builtin_amdgcn_mfma_f32_16x16x32_bf16(af[m], bf, acc[m][s], 0, 0, 0);
      }
    }
#pragma unroll
    for (int m = 0; m < 4; m++) {
#pragma unroll
      for (int s = 0; s < 4; s++) {
        int col = (cw * 4 + s) * 16 + l15;
#pragma unroll
        for (int r = 0; r < 4; r++) {
          float v = acc[m][s][r] + bias[s];
          v = v > 0.0f ? v : 0.0f;
          h1[(size_t)(tb + m * 16 + quad * 4 + r) * H1W + col] = f2bf(v);
        }
      }
    }
  }
}

// ---------------- FFN gemm2 + residual: w2 LDS-stationary, 768 thr ---------
// Full w2 per block (grid 256), 12 waves = 2 token-groups x 6 col-waves x
// 2 col-tiles. af[4] feeds 8 MFMAs; zero main-loop barriers.
__global__ __launch_bounds__(768) void ffn2_kernel(const u16* __restrict__ h1,
    const u16* __restrict__ w2b, const float* __restrict__ b2,
    const u16* __restrict__ att, float* __restrict__ out) {
  __shared__ u16 W2[192 * W2S];  // 150,528 B
  int tid = threadIdx.x;
  for (int i = tid; i < 192 * 48; i += 768) {
    int r = i / 48, sg = i % 48;
    *(uint4*)(W2 + r * W2S + sg * 8) = *(const uint4*)(w2b + r * 384 + sg * 8);
  }
  __syncthreads();
  int wid = tid >> 6, lane = tid & 63;
  int l15 = lane & 15, quad = lane >> 4;
  int tg = (wid >= 6) ? 1 : 0;
  int cw = wid - tg * 6;          // 0..5, owns 2 col-tiles
  int tok0 = (int)blockIdx.x * 256 + tg * 128;
  float bias[2];
  int aoff[2];
#pragma unroll
  for (int s = 0; s < 2; s++) {
    int col = (cw * 2 + s) * 16 + l15;
    bias[s] = b2[col];
    aoff[s] = (col < 48) ? col : ((col < 144) ? col + 48 : col - 96);
  }
#pragma unroll 1
  for (int mc = 0; mc < 2; mc++) {
    int tb = tok0 + mc * 64;
    f32x4 acc[4][2] = {};
#pragma unroll
    for (int kk = 0; kk < 384; kk += 32) {
      bf16x8 af[4];
#pragma unroll
      for (int m = 0; m < 4; m++)
        af[m] = *(const bf16x8*)(h1 + (size_t)(tb + m * 16 + l15) * H1W + kk + quad * 8);
#pragma unroll
      for (int s = 0; s < 2; s++) {
        bf16x8 bf = *(const bf16x8*)(W2 + (size_t)((cw * 2 + s) * 16 + l15) * W2S + kk + quad * 8);
#pragma unroll
        for (int m = 0; m < 4; m++)
          acc[m][s] = __builtin_amdgcn_mfma_f32_16x16x32_bf16(af[m], bf, acc[m][s], 0, 0, 0);
      }
    }
#pragma unroll
    for (int m = 0; m < 4; m++) {
#pragma unroll
      for (int s = 0; s < 2; s++) {
        int col = (cw * 2 + s) * 16 + l15;
#pragma unroll
        for (int r = 0; r < 4; r++) {
          int tok = tb + m * 16 + quad * 4 + r;
          float v = acc[m][s][r] + bias[s];
          v = v > 0.0f ? v : 0.0f;
          out[(size_t)tok * EMB + col] = v + bf2f(att[(size_t)tok * ATTW + aoff[s]]);
        }
      }
    }
  }
}

extern "C" void kernel_launch(void* const* d_in, const int* in_sizes, int n_in,
                              void* d_out, int out_size, void* d_ws, size_t ws_size,
                              hipStream_t stream) {
  const float* x         = (const float*)d_in[0];
  const float* ln1_g     = (const float*)d_in[1];
  const float* ln1_b     = (const float*)d_in[2];
  const float* acc_wqkv  = (const float*)d_in[3];
  const float* acc_bqkv  = (const float*)d_in[4];
  const float* acc_wo    = (const float*)d_in[5];
  const float* acc_bo    = (const float*)d_in[6];
  const float* gyro_wqkv = (const float*)d_in[7];
  const float* gyro_bqkv = (const float*)d_in[8];
  const float* gyro_wo   = (const float*)d_in[9];
  const float* gyro_bo   = (const float*)d_in[10];
  const float* conv_w    = (const float*)d_in[11];
  const float* ln2_g     = (const float*)d_in[12];
  const float* ln2_b     = (const float*)d_in[13];
  const float* w1        = (const float*)d_in[14];
  const float* b1        = (const float*)d_in[15];
  const float* w2        = (const float*)d_in[16];
  const float* b2        = (const float*)d_in[17];
  float* out = (float*)d_out;
  char* ws = (char*)d_ws;

  u16* qkvb = (u16*)(ws);                      // [N,288] bf16  37,748,736
  u16* tnb  = (u16*)(ws);                      // [N,192] bf16  25,165,824 (aliases dead qkvb)
  u16* attb = (u16*)(ws + 37748736);           // [N,192] bf16  25,165,824
  u16* w1b  = (u16*)(ws + 62914560);           // 147,456
  u16* w2b  = (u16*)(ws + 63062016);           // 147,456
  u16* wqp  = (u16*)(ws + 63209472);           // 36,864
  u16* wop  = (u16*)(ws + 63246336);           // 12,288
  u16* h1b  = (u16*)(ws + 63258624);           // [N,384] bf16  50,331,648 -> end 113,590,272

  pack_kernel<<<672, 256, 0, stream>>>(w1, w2, acc_wqkv, gyro_wqkv, acc_wo,
                                       gyro_wo, w1b, w2b, wqp, wop);
  ln1_qkv_conv_kernel<<<NTOK / 32, 256, 0, stream>>>(
      x, ln1_g, ln1_b, wqp, acc_bqkv, gyro_bqkv, conv_w, qkvb, attb);
  attn_kernel<<<NB * 6, 512, 0, stream>>>(qkvb, attb);
  outproj_ln2_kernel<<<NTOK / 64, 256, 0, stream>>>(
      attb, wop, acc_bo, gyro_bo, x, ln2_g, ln2_b, tnb);
  ffn1_kernel<<<256, 768, 0, stream>>>(tnb, w1b, b1, h1b);
  ffn2_kernel<<<256, 768, 0, stream>>>(h1b, w2b, b2, attb, out);
}

// Round 13
// 316.558 us; speedup vs baseline: 1.0456x; 1.0059x over previous
//
#include <hip/hip_runtime.h>
#include <stdint.h>

typedef unsigned short u16;
typedef short bf16x8 __attribute__((ext_vector_type(8)));
typedef float f32x4 __attribute__((ext_vector_type(4)));
typedef float f32x16 __attribute__((ext_vector_type(16)));
typedef uint32_t u32x4 __attribute__((ext_vector_type(4)));

#define NB   128
#define SEQ  512
#define EMB  192
#define NTOK (NB * SEQ)   // 65536
#define F1DIM 384
#define ATTW 192          // att row (u16): x1 cols 0..47 & 144..191 at slots 0..95 after outproj; conv(x1[48:144]) at 96..191
#define VTP  520          // V^T row stride (u16)
#define KTS  24           // K row stride (u16)
#define XnS  200          // xn/x1 LDS row stride (u16): 400B, 16B-aligned
#define TNW  192          // tn global row (u16)
#define H1W  384          // h1 global row (u16)
#define W1S  200          // w1 LDS row stride (u16): 400B, 2-way bank alias only
#define W2S  392          // w2 LDS row stride (u16): 784B, 2-way bank alias only

// raw v_exp_f32: scores are pre-scaled into exp2 domain and bounded.
#if __has_builtin(__builtin_amdgcn_exp2f)
#define EXP2F(x) __builtin_amdgcn_exp2f(x)
#else
#define EXP2F(x) exp2f(x)
#endif

__device__ __forceinline__ float bf2f(u16 u) {
  union { uint32_t u; float f; } v; v.u = ((uint32_t)u) << 16; return v.f;
}
// f32->bf16 via v_cvt_pk_bf16_f32 (1 VALU op, RTNE).
__device__ __forceinline__ u16 f2bf(float f) {
  uint32_t r;
  asm("v_cvt_pk_bf16_f32 %0, %1, %1" : "=v"(r) : "v"(f));
  return (u16)r;
}
__device__ __forceinline__ uint32_t pack2bf(float a, float b) {
  uint32_t r;
  asm("v_cvt_pk_bf16_f32 %0, %1, %2" : "=v"(r) : "v"(a), "v"(b));
  return r;
}

// ---------------- pack all weights (one launch) ----------------------------
__global__ __launch_bounds__(256) void pack_kernel(const float* __restrict__ w1,
    const float* __restrict__ w2, const float* __restrict__ wqa,
    const float* __restrict__ wqg, const float* __restrict__ woa,
    const float* __restrict__ wog, u16* __restrict__ w1b, u16* __restrict__ w2b,
    u16* __restrict__ wqp, u16* __restrict__ wop) {
  int idx = (int)blockIdx.x * 256 + (int)threadIdx.x;
  if (idx < 73728) {
    w1b[idx] = f2bf(w1[idx]);
  } else if (idx < 147456) {
    w2b[idx - 73728] = f2bf(w2[idx - 73728]);
  } else if (idx < 165888) {
    int i = idx - 147456;
    int row = i >> 6, k = i & 63;
    float v = 0.0f;
    if (k < 48) v = (row < 144) ? wqa[row * 48 + k] : wqg[(row - 144) * 48 + k];
    wqp[i] = f2bf(v);
  } else if (idx < 172032) {
    int i = idx - 165888;
    int row = i >> 6, k = i & 63;
    float v = 0.0f;
    if (k < 48) v = (row < 48) ? woa[row * 48 + k] : wog[(row - 48) * 48 + k];
    wop[i] = f2bf(v);
  }
}

// ---------------- fused LN1 + QKV-proj (MFMA) + conv -----------------------
// 32 tokens/block, grid 2048. LDS 12.8KB; LN = 8 thr/token (24 cols);
// MFMA = 4 waves: (m-tile, branch-half) each with acc[9]; conv = 8
// thr/token (12 cols, 26-elem window).
__global__ __launch_bounds__(256) void ln1_qkv_conv_kernel(
    const float* __restrict__ x, const float* __restrict__ g,
    const float* __restrict__ b, const u16* __restrict__ wq,
    const float* __restrict__ bacc, const float* __restrict__ bgyr,
    const float* __restrict__ cw, u16* __restrict__ qkv,
    u16* __restrict__ att) {
  __shared__ u16 Xn[32 * XnS];
  int bm = (int)blockIdx.x * 32;
  int tid = threadIdx.x;
  int trow = tid >> 3, part = tid & 7;
  int tok = bm + trow;
  const float* xr = x + (size_t)tok * EMB + part * 24;
  float vals[24];
#pragma unroll
  for (int j = 0; j < 24; j += 4) {
    float4 v = *(const float4*)(xr + j);
    vals[j] = v.x; vals[j + 1] = v.y; vals[j + 2] = v.z; vals[j + 3] = v.w;
  }
  float s = 0.0f, s2 = 0.0f;
#pragma unroll
  for (int j = 0; j < 24; j++) { s += vals[j]; s2 += vals[j] * vals[j]; }
  s += __shfl_xor(s, 1); s2 += __shfl_xor(s2, 1);
  s += __shfl_xor(s, 2); s2 += __shfl_xor(s2, 2);
  s += __shfl_xor(s, 4); s2 += __shfl_xor(s2, 4);
  float mean = s * (1.0f / EMB);
  float var  = s2 * (1.0f / EMB) - mean * mean;
  float rs   = rsqrtf(var + 1e-6f);
  {
    u16* xnrow = Xn + trow * XnS + part * 24;
    const float* gp = g + part * 24;
    const float* bp = b + part * 24;
#pragma unroll
    for (int j = 0; j < 24; j += 2) {
      uint32_t w = pack2bf((vals[j] - mean) * rs * gp[j] + bp[j],
                           (vals[j + 1] - mean) * rs * gp[j + 1] + bp[j + 1]);
      *(uint32_t*)(xnrow + j) = w;
    }
  }
  __syncthreads();
  int wid = tid >> 6, lane = tid & 63;
  int l15 = lane & 15, quad = lane >> 4;
  {
    int mt = wid & 1, half = wid >> 1;
    const u16* arow_l = Xn + (mt * 16 + l15) * XnS + half * 96;
    const float* bias_p = half ? bgyr : bacc;
    f32x4 acc[9] = {};
#pragma unroll
    for (int ks = 0; ks < 2; ks++) {
      int kk = ks * 32;
      bf16x8 af = *(const bf16x8*)(arow_l + kk + quad * 8);
#pragma unroll
      for (int s9 = 0; s9 < 9; s9++) {
        int st = half * 9 + s9;
        bf16x8 bf = *(const bf16x8*)(wq + (size_t)(st * 16 + l15) * 64 + kk + quad * 8);
        acc[s9] = __builtin_amdgcn_mfma_f32_16x16x32_bf16(af, bf, acc[s9], 0, 0, 0);
      }
    }
#pragma unroll
    for (int s9 = 0; s9 < 9; s9++) {
      int cc = s9 * 16 + l15;             // 0..143 within branch
      int col = half * 144 + cc;
      float bias = bias_p[cc];
      float qs = (cc < 48) ? 0.36067376022f : 1.0f;  // 0.25*log2(e): exp2-domain scores
#pragma unroll
      for (int r = 0; r < 4; r++) {
        int orow = bm + mt * 16 + quad * 4 + r;
        qkv[(size_t)orow * 288 + col] = f2bf((acc[s9][r] + bias) * qs);
      }
    }
  }
  {
    int wr = trow & 3;
    float w15[15];
#pragma unroll
    for (int k = 0; k < 15; k++) w15[k] = cw[wr * 15 + k];
    float win[26];
    int base = part * 12 - 7;
#pragma unroll
    for (int i = 0; i < 26; i++) {
      int p = base + i;
      win[i] = (p >= 0 && p < 96) ? bf2f(Xn[trow * XnS + 48 + p]) : 0.0f;
    }
    const float* xres = x + (size_t)tok * EMB + 48 + part * 12;
    u16* orow = att + (size_t)tok * ATTW + 96 + part * 12;
#pragma unroll
    for (int c = 0; c < 12; c += 4) {
      float4 r4 = *(const float4*)(xres + c);
      float o[4];
#pragma unroll
      for (int u = 0; u < 4; u++) {
        float sc = 0.0f;
#pragma unroll
        for (int k = 0; k < 15; k++) sc += win[c + u + k] * w15[k];
        o[u] = sc;
      }
      *(uint32_t*)(orow + c)     = pack2bf(o[0] + r4.x, o[1] + r4.y);
      *(uint32_t*)(orow + c + 2) = pack2bf(o[2] + r4.z, o[3] + r4.w);
    }
  }
}

// ---------------- MFMA flash attention, max-free exp2 softmax --------------
// 512 thr / 8 waves (2 q-tiles each). permlane32_swap for the cross-half
// P exchange; raw v_exp_f32 via EXP2F.
__global__ __launch_bounds__(512) void attn_kernel(const u16* __restrict__ qkv,
                                                   u16* __restrict__ att) {
  __shared__ u16 Kt[SEQ * KTS];
  __shared__ u16 Vt[17 * VTP];
  int bid = blockIdx.x;
  int hh  = bid % 3;
  int brb = (bid / 3) & 1;
  int b   = bid / 6;
  int tid = threadIdx.x;
  size_t tokbase = (size_t)b * SEQ;
  int qoff = brb * 144 + hh * 16;
  int koff = qoff + 48;
  int voff = qoff + 96;
  {
    int r = tid;  // 512 threads cover SEQ exactly
    const u16* src = qkv + (tokbase + r) * 288;
    *(uint4*)(Kt + r * KTS)     = *(const uint4*)(src + koff);
    *(uint4*)(Kt + r * KTS + 8) = *(const uint4*)(src + koff + 8);
    u16 tmp[16];
    *(uint4*)(tmp)     = *(const uint4*)(src + voff);
    *(uint4*)(tmp + 8) = *(const uint4*)(src + voff + 8);
#pragma unroll
    for (int j = 0; j < 16; j++) Vt[j * VTP + r] = tmp[j];
    Vt[16 * VTP + r] = 0x3F80;  // ones row -> l from the PV MFMA
  }
  __syncthreads();
  int wave = tid >> 6, lane = tid & 63;
  int q31 = lane & 31, h = lane >> 5;
  int dcl = (q31 < 16) ? q31 : 16;
#pragma unroll 1
  for (int qi = 0; qi < 2; qi++) {
    int qrow = (wave * 2 + qi) * 32 + q31;
    bf16x8 qfrag = *(const bf16x8*)(qkv + (tokbase + qrow) * 288 + qoff + h * 8);
    f32x16 Ot = {};
#pragma unroll 2
    for (int kt = 0; kt < 16; kt++) {
      bf16x8 kfrag = *(const bf16x8*)(Kt + (kt * 32 + q31) * KTS + h * 8);
      f32x16 zc = {};
      f32x16 S = __builtin_amdgcn_mfma_f32_32x32x16_bf16(kfrag, qfrag, zc, 0, 0, 0);
      uint32_t pk[8];
#pragma unroll
      for (int i = 0; i < 8; i++) {
        union { float f; uint32_t u; } a0, a1;
        a0.f = EXP2F(S[2 * i]);
        a1.f = EXP2F(S[2 * i + 1]);
        pk[i] = __builtin_amdgcn_perm(a1.u, a0.u, 0x07060302u);
      }
      // permlane32_swap(a,b): a' = {a.lo | b.lo}, b' = {a.hi | b.hi}
      uint32_t s0a = pk[0], s0b = pk[2];
      uint32_t s1a = pk[1], s1b = pk[3];
      uint32_t s2a = pk[4], s2b = pk[6];
      uint32_t s3a = pk[5], s3b = pk[7];
      asm("v_permlane32_swap_b32 %0, %1" : "+v"(s0a), "+v"(s0b));
      asm("v_permlane32_swap_b32 %0, %1" : "+v"(s1a), "+v"(s1b));
      asm("v_permlane32_swap_b32 %0, %1" : "+v"(s2a), "+v"(s2b));
      asm("v_permlane32_swap_b32 %0, %1" : "+v"(s3a), "+v"(s3b));
      u32x4 t1 = { s0a, s1a, s0b, s1b };
      u32x4 t2 = { s2a, s3a, s2b, s3b };
      bf16x8 pb1 = __builtin_bit_cast(bf16x8, t1);
      bf16x8 pb2 = __builtin_bit_cast(bf16x8, t2);
      bf16x8 av1 = *(const bf16x8*)(Vt + dcl * VTP + kt * 32 + h * 8);
      bf16x8 av2 = *(const bf16x8*)(Vt + dcl * VTP + kt * 32 + 16 + h * 8);
      Ot = __builtin_amdgcn_mfma_f32_32x32x16_bf16(av1, pb1, Ot, 0, 0, 0);
      Ot = __builtin_amdgcn_mfma_f32_32x32x16_bf16(av2, pb2, Ot, 0, 0, 0);
    }
    float inv = 1.0f / Ot[8];
    u16* orow = att + (tokbase + qrow) * ATTW + brb * 48 + hh * 16 + 4 * h;
    uint2 st0 = { pack2bf(Ot[0] * inv, Ot[1] * inv),
                  pack2bf(Ot[2] * inv, Ot[3] * inv) };
    uint2 st1 = { pack2bf(Ot[4] * inv, Ot[5] * inv),
                  pack2bf(Ot[6] * inv, Ot[7] * inv) };
    *(uint2*)(orow)     = st0;
    *(uint2*)(orow + 8) = st1;
  }
}

// ---------------- out-proj + residual + LN2 -> tn --------------------------
__global__ __launch_bounds__(256) void outproj_ln2_kernel(
    u16* __restrict__ att, const u16* __restrict__ wo,
    const float* __restrict__ boacc, const float* __restrict__ bogyr,
    const float* __restrict__ x, const float* __restrict__ g2,
    const float* __restrict__ b2v, u16* __restrict__ tn) {
  __shared__ u16 X1[64 * XnS];
  int bm = (int)blockIdx.x * 64;
  int tid = threadIdx.x;
  int wid = tid >> 6, lane = tid & 63;
  int l15 = lane & 15, quad = lane >> 4;
  if (wid < 2) {
    bf16x8 wf[2][3];
#pragma unroll
    for (int s = 0; s < 3; s++) {
      int st = wid * 3 + s;
#pragma unroll
      for (int ks = 0; ks < 2; ks++)
        wf[ks][s] = *(const bf16x8*)(wo + (size_t)(st * 16 + l15) * 64 + ks * 32 + quad * 8);
    }
    f32x4 acc[4][3] = {};
#pragma unroll
    for (int m = 0; m < 4; m++) {
      const u16* ar = att + (size_t)(bm + m * 16 + l15) * ATTW + (wid ? 48 : 0);
#pragma unroll
      for (int ks = 0; ks < 2; ks++) {
        bf16x8 af = *(const bf16x8*)(ar + ks * 32 + quad * 8);
#pragma unroll
        for (int s = 0; s < 3; s++)
          acc[m][s] = __builtin_amdgcn_mfma_f32_16x16x32_bf16(af, wf[ks][s], acc[m][s], 0, 0, 0);
      }
    }
#pragma unroll
    for (int s = 0; s < 3; s++) {
      int col = (wid * 3 + s) * 16 + l15;          // 0..95 (att slot)
      float bias = (col < 48) ? boacc[col] : bogyr[col - 48];
      int oc = (col < 48) ? col : col + 96;        // x1 column
#pragma unroll
      for (int m = 0; m < 4; m++) {
#pragma unroll
        for (int r = 0; r < 4; r++) {
          int lrow = m * 16 + quad * 4 + r;
          float v = acc[m][s][r] + bias + x[(size_t)(bm + lrow) * EMB + oc];
          u16 bv = f2bf(v);
          X1[lrow * XnS + oc] = bv;
          att[(size_t)(bm + lrow) * ATTW + col] = bv;
        }
      }
    }
  } else {
    int trow = (wid - 2) * 32 + (lane >> 1);
    int half = lane & 1;
    const u16* src = att + (size_t)(bm + trow) * ATTW + 96 + half * 48;
    u16* dst = X1 + trow * XnS + 48 + half * 48;
#pragma unroll
    for (int j = 0; j < 48; j += 8)
      *(uint4*)(dst + j) = *(const uint4*)(src + j);
  }
  __syncthreads();
  // LN2: 4 threads/token, 48 cols each
  {
    int trow = tid >> 2, part = tid & 3;
    const u16* xl = X1 + trow * XnS + part * 48;
    float vals[48];
#pragma unroll
    for (int j = 0; j < 48; j += 8) {
      u16 raw[8];
      *(uint4*)raw = *(const uint4*)(xl + j);
#pragma unroll
      for (int u = 0; u < 8; u++) vals[j + u] = bf2f(raw[u]);
    }
    float s = 0.0f, s2 = 0.0f;
#pragma unroll
    for (int j = 0; j < 48; j++) { s += vals[j]; s2 += vals[j] * vals[j]; }
    s += __shfl_xor(s, 1); s2 += __shfl_xor(s2, 1);
    s += __shfl_xor(s, 2); s2 += __shfl_xor(s2, 2);
    float mean = s * (1.0f / EMB);
    float var  = s2 * (1.0f / EMB) - mean * mean;
    float rs   = rsqrtf(var + 1e-6f);
    const float* gp = g2 + part * 48;
    const float* bp = b2v + part * 48;
    u16 obuf[48];
#pragma unroll
    for (int j = 0; j < 48; j += 2) {
      uint32_t w = pack2bf((vals[j] - mean) * rs * gp[j] + bp[j],
                           (vals[j + 1] - mean) * rs * gp[j + 1] + bp[j + 1]);
      *(uint32_t*)(obuf + j) = w;
    }
    u16* tr = tn + (size_t)(bm + trow) * TNW + part * 48;
#pragma unroll
    for (int j = 0; j < 48; j += 8)
      *(uint4*)(tr + j) = *(const uint4*)(obuf + j);
  }
}

// ---------------- FFN gemm1: w1 LDS-stationary, 768 thr = 12 waves ---------
// Full w1 staged per block (grid 256 = 1 block/CU), 12 waves = 2 token-groups
// x 6 col-waves. Each wave: 4 col-tiles, af[4] feeds 16 MFMAs. Zero main-loop
// barriers.
__global__ __launch_bounds__(768) void ffn1_kernel(const u16* __restrict__ tn,
    const u16* __restrict__ w1b, const float* __restrict__ b1,
    u16* __restrict__ h1) {
  __shared__ u16 W1[384 * W1S];  // 153,600 B
  int tid = threadIdx.x;
  for (int i = tid; i < 384 * 24; i += 768) {
    int r = i / 24, sg = i % 24;
    *(uint4*)(W1 + r * W1S + sg * 8) = *(const uint4*)(w1b + r * 192 + sg * 8);
  }
  __syncthreads();
  int wid = tid >> 6, lane = tid & 63;
  int l15 = lane & 15, quad = lane >> 4;
  int tg = (wid >= 6) ? 1 : 0;
  int cw = wid - tg * 6;          // 0..5, owns 4 col-tiles
  int tok0 = (int)blockIdx.x * 256 + tg * 128;
  float bias[4];
#pragma unroll
  for (int s = 0; s < 4; s++) bias[s] = b1[(cw * 4 + s) * 16 + l15];
#pragma unroll 1
  for (int mc = 0; mc < 2; mc++) {
    int tb = tok0 + mc * 64;
    f32x4 acc[4][4] = {};
#pragma unroll
    for (int kk = 0; kk < 192; kk += 32) {
      bf16x8 af[4];
#pragma unroll
      for (int m = 0; m < 4; m++)
        af[m] = *(const bf16x8*)(tn + (size_t)(tb + m * 16 + l15) * TNW + kk + quad * 8);
#pragma unroll
      for (int s = 0; s < 4; s++) {
        bf16x8 bf = *(const bf16x8*)(W1 + (size_t)((cw * 4 + s) * 16 + l15) * W1S + kk + quad * 8);
#pragma unroll
        for (int m = 0; m < 4; m++)
          acc[m][s] = __builtin_amdgcn_mfma_f32_16x16x32_bf16(af[m], bf, acc[m][s], 0, 0, 0);
      }
    }
#pragma unroll
    for (int m = 0; m < 4; m++) {
#pragma unroll
      for (int s = 0; s < 4; s++) {
        int col = (cw * 4 + s) * 16 + l15;
#pragma unroll
        for (int r = 0; r < 4; r++) {
          float v = acc[m][s][r] + bias[s];
          v = v > 0.0f ? v : 0.0f;
          h1[(size_t)(tb + m * 16 + quad * 4 + r) * H1W + col] = f2bf(v);
        }
      }
    }
  }
}

// ---------------- FFN gemm2 + residual: w2 LDS-stationary, 768 thr ---------
// Round 13: mc loop folded into the fragment batch — each wave computes
// 8 m-tiles x 2 col-tiles (af[8] -> 16 MFMAs per kk). 8 independent global
// loads issue before any MFMA consumes them; fully-unrolled kk loop lets
// next step's loads fly under current step's MFMAs. FFN kernels proved
// NOT TLP-limited (occupancy 13.8->28.5 with dur flat/worse r8->r12) —
// per-wave load ILP is the lever. acc[8][2]=64 + af[8]=32 VGPR, ~120 total.
__global__ __launch_bounds__(768) void ffn2_kernel(const u16* __restrict__ h1,
    const u16* __restrict__ w2b, const float* __restrict__ b2,
    const u16* __restrict__ att, float* __restrict__ out) {
  __shared__ u16 W2[192 * W2S];  // 150,528 B
  int tid = threadIdx.x;
  for (int i = tid; i < 192 * 48; i += 768) {
    int r = i / 48, sg = i % 48;
    *(uint4*)(W2 + r * W2S + sg * 8) = *(const uint4*)(w2b + r * 384 + sg * 8);
  }
  __syncthreads();
  int wid = tid >> 6, lane = tid & 63;
  int l15 = lane & 15, quad = lane >> 4;
  int tg = (wid >= 6) ? 1 : 0;
  int cw = wid - tg * 6;          // 0..5, owns 2 col-tiles
  int tb = (int)blockIdx.x * 256 + tg * 128;
  float bias[2];
  int aoff[2];
#pragma unroll
  for (int s = 0; s < 2; s++) {
    int col = (cw * 2 + s) * 16 + l15;
    bias[s] = b2[col];
    aoff[s] = (col < 48) ? col : ((col < 144) ? col + 48 : col - 96);
  }
  f32x4 acc[8][2] = {};
#pragma unroll
  for (int kk = 0; kk < 384; kk += 32) {
    bf16x8 af[8];
#pragma unroll
    for (int m = 0; m < 8; m++)
      af[m] = *(const bf16x8*)(h1 + (size_t)(tb + m * 16 + l15) * H1W + kk + quad * 8);
#pragma unroll
    for (int s = 0; s < 2; s++) {
      bf16x8 bf = *(const bf16x8*)(W2 + (size_t)((cw * 2 + s) * 16 + l15) * W2S + kk + quad * 8);
#pragma unroll
      for (int m = 0; m < 8; m++)
        acc[m][s] = __builtin_amdgcn_mfma_f32_16x16x32_bf16(af[m], bf, acc[m][s], 0, 0, 0);
    }
  }
#pragma unroll
  for (int m = 0; m < 8; m++) {
#pragma unroll
    for (int s = 0; s < 2; s++) {
      int col = (cw * 2 + s) * 16 + l15;
#pragma unroll
      for (int r = 0; r < 4; r++) {
        int tok = tb + m * 16 + quad * 4 + r;
        float v = acc[m][s][r] + bias[s];
        v = v > 0.0f ? v : 0.0f;
        out[(size_t)tok * EMB + col] = v + bf2f(att[(size_t)tok * ATTW + aoff[s]]);
      }
    }
  }
}

extern "C" void kernel_launch(void* const* d_in, const int* in_sizes, int n_in,
                              void* d_out, int out_size, void* d_ws, size_t ws_size,
                              hipStream_t stream) {
  const float* x         = (const float*)d_in[0];
  const float* ln1_g     = (const float*)d_in[1];
  const float* ln1_b     = (const float*)d_in[2];
  const float* acc_wqkv  = (const float*)d_in[3];
  const float* acc_bqkv  = (const float*)d_in[4];
  const float* acc_wo    = (const float*)d_in[5];
  const float* acc_bo    = (const float*)d_in[6];
  const float* gyro_wqkv = (const float*)d_in[7];
  const float* gyro_bqkv = (const float*)d_in[8];
  const float* gyro_wo   = (const float*)d_in[9];
  const float* gyro_bo   = (const float*)d_in[10];
  const float* conv_w    = (const float*)d_in[11];
  const float* ln2_g     = (const float*)d_in[12];
  const float* ln2_b     = (const float*)d_in[13];
  const float* w1        = (const float*)d_in[14];
  const float* b1        = (const float*)d_in[15];
  const float* w2        = (const float*)d_in[16];
  const float* b2        = (const float*)d_in[17];
  float* out = (float*)d_out;
  char* ws = (char*)d_ws;

  u16* qkvb = (u16*)(ws);                      // [N,288] bf16  37,748,736
  u16* tnb  = (u16*)(ws);                      // [N,192] bf16  25,165,824 (aliases dead qkvb)
  u16* attb = (u16*)(ws + 37748736);           // [N,192] bf16  25,165,824
  u16* w1b  = (u16*)(ws + 62914560);           // 147,456
  u16* w2b  = (u16*)(ws + 63062016);           // 147,456
  u16* wqp  = (u16*)(ws + 63209472);           // 36,864
  u16* wop  = (u16*)(ws + 63246336);           // 12,288
  u16* h1b  = (u16*)(ws + 63258624);           // [N,384] bf16  50,331,648 -> end 113,590,272

  pack_kernel<<<672, 256, 0, stream>>>(w1, w2, acc_wqkv, gyro_wqkv, acc_wo,
                                       gyro_wo, w1b, w2b, wqp, wop);
  ln1_qkv_conv_kernel<<<NTOK / 32, 256, 0, stream>>>(
      x, ln1_g, ln1_b, wqp, acc_bqkv, gyro_bqkv, conv_w, qkvb, attb);
  attn_kernel<<<NB * 6, 512, 0, stream>>>(qkvb, attb);
  outproj_ln2_kernel<<<NTOK / 64, 256, 0, stream>>>(
      attb, wop, acc_bo, gyro_bo, x, ln2_g, ln2_b, tnb);
  ffn1_kernel<<<256, 768, 0, stream>>>(tnb, w1b, b1, h1b);
  ffn2_kernel<<<256, 768, 0, stream>>>(h1b, w2b, b2, attb, out);
}

// Round 14
// 299.559 us; speedup vs baseline: 1.1050x; 1.0567x over previous
//
#include <hip/hip_runtime.h>
#include <stdint.h>

typedef unsigned short u16;
typedef short bf16x8 __attribute__((ext_vector_type(8)));
typedef float f32x4 __attribute__((ext_vector_type(4)));
typedef float f32x16 __attribute__((ext_vector_type(16)));
typedef uint32_t u32x4 __attribute__((ext_vector_type(4)));

#define NB   128
#define SEQ  512
#define EMB  192
#define NTOK (NB * SEQ)   // 65536
#define F1DIM 384
#define ATTW 192          // att row (u16): x1 cols 0..47 & 144..191 at slots 0..95 after outproj; conv(x1[48:144]) at 96..191
#define VTP  520          // V^T row stride (u16)
#define KTS  24           // K row stride (u16)
#define XnS  200          // xn/x1 LDS row stride (u16): 400B, 16B-aligned
#define TNW  192          // tn global row (u16)
#define H1W  384          // h1 global row (u16)
#define W1S  200          // w1 LDS row stride (u16): 400B, 2-way bank alias only
#define W2S  392          // w2 LDS row stride (u16): 784B, 2-way bank alias only

// raw v_exp_f32: scores are pre-scaled into exp2 domain and bounded.
#if __has_builtin(__builtin_amdgcn_exp2f)
#define EXP2F(x) __builtin_amdgcn_exp2f(x)
#else
#define EXP2F(x) exp2f(x)
#endif

__device__ __forceinline__ float bf2f(u16 u) {
  union { uint32_t u; float f; } v; v.u = ((uint32_t)u) << 16; return v.f;
}
// f32->bf16 via v_cvt_pk_bf16_f32 (1 VALU op, RTNE).
__device__ __forceinline__ u16 f2bf(float f) {
  uint32_t r;
  asm("v_cvt_pk_bf16_f32 %0, %1, %1" : "=v"(r) : "v"(f));
  return (u16)r;
}
__device__ __forceinline__ uint32_t pack2bf(float a, float b) {
  uint32_t r;
  asm("v_cvt_pk_bf16_f32 %0, %1, %2" : "=v"(r) : "v"(a), "v"(b));
  return r;
}

// ---------------- pack all weights (one launch) ----------------------------
__global__ __launch_bounds__(256) void pack_kernel(const float* __restrict__ w1,
    const float* __restrict__ w2, const float* __restrict__ wqa,
    const float* __restrict__ wqg, const float* __restrict__ woa,
    const float* __restrict__ wog, u16* __restrict__ w1b, u16* __restrict__ w2b,
    u16* __restrict__ wqp, u16* __restrict__ wop) {
  int idx = (int)blockIdx.x * 256 + (int)threadIdx.x;
  if (idx < 73728) {
    w1b[idx] = f2bf(w1[idx]);
  } else if (idx < 147456) {
    w2b[idx - 73728] = f2bf(w2[idx - 73728]);
  } else if (idx < 165888) {
    int i = idx - 147456;
    int row = i >> 6, k = i & 63;
    float v = 0.0f;
    if (k < 48) v = (row < 144) ? wqa[row * 48 + k] : wqg[(row - 144) * 48 + k];
    wqp[i] = f2bf(v);
  } else if (idx < 172032) {
    int i = idx - 165888;
    int row = i >> 6, k = i & 63;
    float v = 0.0f;
    if (k < 48) v = (row < 48) ? woa[row * 48 + k] : wog[(row - 48) * 48 + k];
    wop[i] = f2bf(v);
  }
}

// ---------------- fused LN1 + QKV-proj (MFMA) + conv -----------------------
// 32 tokens/block, grid 2048. LDS 12.8KB; LN = 8 thr/token (24 cols);
// MFMA = 4 waves: (m-tile, branch-half) each with acc[9]; conv = 8
// thr/token (12 cols, 26-elem window).
__global__ __launch_bounds__(256) void ln1_qkv_conv_kernel(
    const float* __restrict__ x, const float* __restrict__ g,
    const float* __restrict__ b, const u16* __restrict__ wq,
    const float* __restrict__ bacc, const float* __restrict__ bgyr,
    const float* __restrict__ cw, u16* __restrict__ qkv,
    u16* __restrict__ att) {
  __shared__ u16 Xn[32 * XnS];
  int bm = (int)blockIdx.x * 32;
  int tid = threadIdx.x;
  int trow = tid >> 3, part = tid & 7;
  int tok = bm + trow;
  const float* xr = x + (size_t)tok * EMB + part * 24;
  float vals[24];
#pragma unroll
  for (int j = 0; j < 24; j += 4) {
    float4 v = *(const float4*)(xr + j);
    vals[j] = v.x; vals[j + 1] = v.y; vals[j + 2] = v.z; vals[j + 3] = v.w;
  }
  float s = 0.0f, s2 = 0.0f;
#pragma unroll
  for (int j = 0; j < 24; j++) { s += vals[j]; s2 += vals[j] * vals[j]; }
  s += __shfl_xor(s, 1); s2 += __shfl_xor(s2, 1);
  s += __shfl_xor(s, 2); s2 += __shfl_xor(s2, 2);
  s += __shfl_xor(s, 4); s2 += __shfl_xor(s2, 4);
  float mean = s * (1.0f / EMB);
  float var  = s2 * (1.0f / EMB) - mean * mean;
  float rs   = rsqrtf(var + 1e-6f);
  {
    u16* xnrow = Xn + trow * XnS + part * 24;
    const float* gp = g + part * 24;
    const float* bp = b + part * 24;
#pragma unroll
    for (int j = 0; j < 24; j += 2) {
      uint32_t w = pack2bf((vals[j] - mean) * rs * gp[j] + bp[j],
                           (vals[j + 1] - mean) * rs * gp[j + 1] + bp[j + 1]);
      *(uint32_t*)(xnrow + j) = w;
    }
  }
  __syncthreads();
  int wid = tid >> 6, lane = tid & 63;
  int l15 = lane & 15, quad = lane >> 4;
  {
    int mt = wid & 1, half = wid >> 1;
    const u16* arow_l = Xn + (mt * 16 + l15) * XnS + half * 96;
    const float* bias_p = half ? bgyr : bacc;
    f32x4 acc[9] = {};
#pragma unroll
    for (int ks = 0; ks < 2; ks++) {
      int kk = ks * 32;
      bf16x8 af = *(const bf16x8*)(arow_l + kk + quad * 8);
#pragma unroll
      for (int s9 = 0; s9 < 9; s9++) {
        int st = half * 9 + s9;
        bf16x8 bf = *(const bf16x8*)(wq + (size_t)(st * 16 + l15) * 64 + kk + quad * 8);
        acc[s9] = __builtin_amdgcn_mfma_f32_16x16x32_bf16(af, bf, acc[s9], 0, 0, 0);
      }
    }
#pragma unroll
    for (int s9 = 0; s9 < 9; s9++) {
      int cc = s9 * 16 + l15;             // 0..143 within branch
      int col = half * 144 + cc;
      float bias = bias_p[cc];
      float qs = (cc < 48) ? 0.36067376022f : 1.0f;  // 0.25*log2(e): exp2-domain scores
#pragma unroll
      for (int r = 0; r < 4; r++) {
        int orow = bm + mt * 16 + quad * 4 + r;
        qkv[(size_t)orow * 288 + col] = f2bf((acc[s9][r] + bias) * qs);
      }
    }
  }
  {
    int wr = trow & 3;
    float w15[15];
#pragma unroll
    for (int k = 0; k < 15; k++) w15[k] = cw[wr * 15 + k];
    float win[26];
    int base = part * 12 - 7;
#pragma unroll
    for (int i = 0; i < 26; i++) {
      int p = base + i;
      win[i] = (p >= 0 && p < 96) ? bf2f(Xn[trow * XnS + 48 + p]) : 0.0f;
    }
    const float* xres = x + (size_t)tok * EMB + 48 + part * 12;
    u16* orow = att + (size_t)tok * ATTW + 96 + part * 12;
#pragma unroll
    for (int c = 0; c < 12; c += 4) {
      float4 r4 = *(const float4*)(xres + c);
      float o[4];
#pragma unroll
      for (int u = 0; u < 4; u++) {
        float sc = 0.0f;
#pragma unroll
        for (int k = 0; k < 15; k++) sc += win[c + u + k] * w15[k];
        o[u] = sc;
      }
      *(uint32_t*)(orow + c)     = pack2bf(o[0] + r4.x, o[1] + r4.y);
      *(uint32_t*)(orow + c + 2) = pack2bf(o[2] + r4.z, o[3] + r4.w);
    }
  }
}

// ---------------- MFMA flash attention, max-free exp2 softmax --------------
// 512 thr / 8 waves (2 q-tiles each). permlane32_swap for the cross-half
// P exchange; raw v_exp_f32 via EXP2F.
__global__ __launch_bounds__(512) void attn_kernel(const u16* __restrict__ qkv,
                                                   u16* __restrict__ att) {
  __shared__ u16 Kt[SEQ * KTS];
  __shared__ u16 Vt[17 * VTP];
  int bid = blockIdx.x;
  int hh  = bid % 3;
  int brb = (bid / 3) & 1;
  int b   = bid / 6;
  int tid = threadIdx.x;
  size_t tokbase = (size_t)b * SEQ;
  int qoff = brb * 144 + hh * 16;
  int koff = qoff + 48;
  int voff = qoff + 96;
  {
    int r = tid;  // 512 threads cover SEQ exactly
    const u16* src = qkv + (tokbase + r) * 288;
    *(uint4*)(Kt + r * KTS)     = *(const uint4*)(src + koff);
    *(uint4*)(Kt + r * KTS + 8) = *(const uint4*)(src + koff + 8);
    u16 tmp[16];
    *(uint4*)(tmp)     = *(const uint4*)(src + voff);
    *(uint4*)(tmp + 8) = *(const uint4*)(src + voff + 8);
#pragma unroll
    for (int j = 0; j < 16; j++) Vt[j * VTP + r] = tmp[j];
    Vt[16 * VTP + r] = 0x3F80;  // ones row -> l from the PV MFMA
  }
  __syncthreads();
  int wave = tid >> 6, lane = tid & 63;
  int q31 = lane & 31, h = lane >> 5;
  int dcl = (q31 < 16) ? q31 : 16;
#pragma unroll 1
  for (int qi = 0; qi < 2; qi++) {
    int qrow = (wave * 2 + qi) * 32 + q31;
    bf16x8 qfrag = *(const bf16x8*)(qkv + (tokbase + qrow) * 288 + qoff + h * 8);
    f32x16 Ot = {};
#pragma unroll 2
    for (int kt = 0; kt < 16; kt++) {
      bf16x8 kfrag = *(const bf16x8*)(Kt + (kt * 32 + q31) * KTS + h * 8);
      f32x16 zc = {};
      f32x16 S = __builtin_amdgcn_mfma_f32_32x32x16_bf16(kfrag, qfrag, zc, 0, 0, 0);
      uint32_t pk[8];
#pragma unroll
      for (int i = 0; i < 8; i++) {
        union { float f; uint32_t u; } a0, a1;
        a0.f = EXP2F(S[2 * i]);
        a1.f = EXP2F(S[2 * i + 1]);
        pk[i] = __builtin_amdgcn_perm(a1.u, a0.u, 0x07060302u);
      }
      // permlane32_swap(a,b): a' = {a.lo | b.lo}, b' = {a.hi | b.hi}
      uint32_t s0a = pk[0], s0b = pk[2];
      uint32_t s1a = pk[1], s1b = pk[3];
      uint32_t s2a = pk[4], s2b = pk[6];
      uint32_t s3a = pk[5], s3b = pk[7];
      asm("v_permlane32_swap_b32 %0, %1" : "+v"(s0a), "+v"(s0b));
      asm("v_permlane32_swap_b32 %0, %1" : "+v"(s1a), "+v"(s1b));
      asm("v_permlane32_swap_b32 %0, %1" : "+v"(s2a), "+v"(s2b));
      asm("v_permlane32_swap_b32 %0, %1" : "+v"(s3a), "+v"(s3b));
      u32x4 t1 = { s0a, s1a, s0b, s1b };
      u32x4 t2 = { s2a, s3a, s2b, s3b };
      bf16x8 pb1 = __builtin_bit_cast(bf16x8, t1);
      bf16x8 pb2 = __builtin_bit_cast(bf16x8, t2);
      bf16x8 av1 = *(const bf16x8*)(Vt + dcl * VTP + kt * 32 + h * 8);
      bf16x8 av2 = *(const bf16x8*)(Vt + dcl * VTP + kt * 32 + 16 + h * 8);
      Ot = __builtin_amdgcn_mfma_f32_32x32x16_bf16(av1, pb1, Ot, 0, 0, 0);
      Ot = __builtin_amdgcn_mfma_f32_32x32x16_bf16(av2, pb2, Ot, 0, 0, 0);
    }
    float inv = 1.0f / Ot[8];
    u16* orow = att + (tokbase + qrow) * ATTW + brb * 48 + hh * 16 + 4 * h;
    uint2 st0 = { pack2bf(Ot[0] * inv, Ot[1] * inv),
                  pack2bf(Ot[2] * inv, Ot[3] * inv) };
    uint2 st1 = { pack2bf(Ot[4] * inv, Ot[5] * inv),
                  pack2bf(Ot[6] * inv, Ot[7] * inv) };
    *(uint2*)(orow)     = st0;
    *(uint2*)(orow + 8) = st1;
  }
}

// ---------------- out-proj + residual + LN2 -> tn --------------------------
__global__ __launch_bounds__(256) void outproj_ln2_kernel(
    u16* __restrict__ att, const u16* __restrict__ wo,
    const float* __restrict__ boacc, const float* __restrict__ bogyr,
    const float* __restrict__ x, const float* __restrict__ g2,
    const float* __restrict__ b2v, u16* __restrict__ tn) {
  __shared__ u16 X1[64 * XnS];
  int bm = (int)blockIdx.x * 64;
  int tid = threadIdx.x;
  int wid = tid >> 6, lane = tid & 63;
  int l15 = lane & 15, quad = lane >> 4;
  if (wid < 2) {
    bf16x8 wf[2][3];
#pragma unroll
    for (int s = 0; s < 3; s++) {
      int st = wid * 3 + s;
#pragma unroll
      for (int ks = 0; ks < 2; ks++)
        wf[ks][s] = *(const bf16x8*)(wo + (size_t)(st * 16 + l15) * 64 + ks * 32 + quad * 8);
    }
    f32x4 acc[4][3] = {};
#pragma unroll
    for (int m = 0; m < 4; m++) {
      const u16* ar = att + (size_t)(bm + m * 16 + l15) * ATTW + (wid ? 48 : 0);
#pragma unroll
      for (int ks = 0; ks < 2; ks++) {
        bf16x8 af = *(const bf16x8*)(ar + ks * 32 + quad * 8);
#pragma unroll
        for (int s = 0; s < 3; s++)
          acc[m][s] = __builtin_amdgcn_mfma_f32_16x16x32_bf16(af, wf[ks][s], acc[m][s], 0, 0, 0);
      }
    }
#pragma unroll
    for (int s = 0; s < 3; s++) {
      int col = (wid * 3 + s) * 16 + l15;          // 0..95 (att slot)
      float bias = (col < 48) ? boacc[col] : bogyr[col - 48];
      int oc = (col < 48) ? col : col + 96;        // x1 column
#pragma unroll
      for (int m = 0; m < 4; m++) {
#pragma unroll
        for (int r = 0; r < 4; r++) {
          int lrow = m * 16 + quad * 4 + r;
          float v = acc[m][s][r] + bias + x[(size_t)(bm + lrow) * EMB + oc];
          u16 bv = f2bf(v);
          X1[lrow * XnS + oc] = bv;
          att[(size_t)(bm + lrow) * ATTW + col] = bv;
        }
      }
    }
  } else {
    int trow = (wid - 2) * 32 + (lane >> 1);
    int half = lane & 1;
    const u16* src = att + (size_t)(bm + trow) * ATTW + 96 + half * 48;
    u16* dst = X1 + trow * XnS + 48 + half * 48;
#pragma unroll
    for (int j = 0; j < 48; j += 8)
      *(uint4*)(dst + j) = *(const uint4*)(src + j);
  }
  __syncthreads();
  // LN2: 4 threads/token, 48 cols each
  {
    int trow = tid >> 2, part = tid & 3;
    const u16* xl = X1 + trow * XnS + part * 48;
    float vals[48];
#pragma unroll
    for (int j = 0; j < 48; j += 8) {
      u16 raw[8];
      *(uint4*)raw = *(const uint4*)(xl + j);
#pragma unroll
      for (int u = 0; u < 8; u++) vals[j + u] = bf2f(raw[u]);
    }
    float s = 0.0f, s2 = 0.0f;
#pragma unroll
    for (int j = 0; j < 48; j++) { s += vals[j]; s2 += vals[j] * vals[j]; }
    s += __shfl_xor(s, 1); s2 += __shfl_xor(s2, 1);
    s += __shfl_xor(s, 2); s2 += __shfl_xor(s2, 2);
    float mean = s * (1.0f / EMB);
    float var  = s2 * (1.0f / EMB) - mean * mean;
    float rs   = rsqrtf(var + 1e-6f);
    const float* gp = g2 + part * 48;
    const float* bp = b2v + part * 48;
    u16 obuf[48];
#pragma unroll
    for (int j = 0; j < 48; j += 2) {
      uint32_t w = pack2bf((vals[j] - mean) * rs * gp[j] + bp[j],
                           (vals[j + 1] - mean) * rs * gp[j + 1] + bp[j + 1]);
      *(uint32_t*)(obuf + j) = w;
    }
    u16* tr = tn + (size_t)(bm + trow) * TNW + part * 48;
#pragma unroll
    for (int j = 0; j < 48; j += 8)
      *(uint4*)(tr + j) = *(const uint4*)(obuf + j);
  }
}

// ---------------- FFN gemm1: w1 LDS-stationary (round-8 shape) -------------
// REVERT to the best-measured config (r8, ffn2@50.5 era): 512 thr / 8 waves,
// grid 256 = 1 block/CU. Each wave: 3 col-tiles, mc loop 4 x {12 kk x
// (4 loads + 12 MFMA)}. r10's 768-thr token-group split REGRESSED ffn2
// 50.5->58.7 and r13's ILP batch was null (compiler resequenced, VGPR 76).
// Zero main-loop barriers.
__global__ __launch_bounds__(512) void ffn1_kernel(const u16* __restrict__ tn,
    const u16* __restrict__ w1b, const float* __restrict__ b1,
    u16* __restrict__ h1) {
  __shared__ u16 W1[384 * W1S];  // 153,600 B
  int tid = threadIdx.x;
  for (int i = tid; i < 384 * 24; i += 512) {
    int r = i / 24, sg = i % 24;
    *(uint4*)(W1 + r * W1S + sg * 8) = *(const uint4*)(w1b + r * 192 + sg * 8);
  }
  __syncthreads();
  int wid = tid >> 6, lane = tid & 63;
  int l15 = lane & 15, quad = lane >> 4;
  int tok0 = (int)blockIdx.x * 256;
  float bias[3];
#pragma unroll
  for (int s = 0; s < 3; s++) bias[s] = b1[(wid * 3 + s) * 16 + l15];
#pragma unroll 1
  for (int mc = 0; mc < 4; mc++) {
    int tb = tok0 + mc * 64;
    f32x4 acc[4][3] = {};
#pragma unroll
    for (int kk = 0; kk < 192; kk += 32) {
      bf16x8 af[4];
#pragma unroll
      for (int m = 0; m < 4; m++)
        af[m] = *(const bf16x8*)(tn + (size_t)(tb + m * 16 + l15) * TNW + kk + quad * 8);
#pragma unroll
      for (int s = 0; s < 3; s++) {
        bf16x8 bf = *(const bf16x8*)(W1 + (size_t)((wid * 3 + s) * 16 + l15) * W1S + kk + quad * 8);
#pragma unroll
        for (int m = 0; m < 4; m++)
          acc[m][s] = __builtin_amdgcn_mfma_f32_16x16x32_bf16(af[m], bf, acc[m][s], 0, 0, 0);
      }
    }
#pragma unroll
    for (int m = 0; m < 4; m++) {
#pragma unroll
      for (int s = 0; s < 3; s++) {
        int col = (wid * 3 + s) * 16 + l15;
#pragma unroll
        for (int r = 0; r < 4; r++) {
          float v = acc[m][s][r] + bias[s];
          v = v > 0.0f ? v : 0.0f;
          h1[(size_t)(tb + m * 16 + quad * 4 + r) * H1W + col] = f2bf(v);
        }
      }
    }
  }
}

// ---------------- FFN gemm2 + residual: w2 LDS-stationary (round-8 shape) --
// REVERT to best-measured: 384 thr / 6 waves (2 col-tiles each), grid 256,
// mc loop 4 x {12 kk x (4 loads + 8 MFMA)}. Measured 50.5us in r8 vs 57-59
// in the 768-thr variants (r12/r13).
__global__ __launch_bounds__(384) void ffn2_kernel(const u16* __restrict__ h1,
    const u16* __restrict__ w2b, const float* __restrict__ b2,
    const u16* __restrict__ att, float* __restrict__ out) {
  __shared__ u16 W2[192 * W2S];  // 150,528 B
  int tid = threadIdx.x;
  for (int i = tid; i < 192 * 48; i += 384) {
    int r = i / 48, sg = i % 48;
    *(uint4*)(W2 + r * W2S + sg * 8) = *(const uint4*)(w2b + r * 384 + sg * 8);
  }
  __syncthreads();
  int wid = tid >> 6, lane = tid & 63;
  int l15 = lane & 15, quad = lane >> 4;
  int tok0 = (int)blockIdx.x * 256;
  float bias[2];
  int aoff[2];
#pragma unroll
  for (int s = 0; s < 2; s++) {
    int col = (wid * 2 + s) * 16 + l15;
    bias[s] = b2[col];
    aoff[s] = (col < 48) ? col : ((col < 144) ? col + 48 : col - 96);
  }
#pragma unroll 1
  for (int mc = 0; mc < 4; mc++) {
    int tb = tok0 + mc * 64;
    f32x4 acc[4][2] = {};
#pragma unroll
    for (int kk = 0; kk < 384; kk += 32) {
      bf16x8 af[4];
#pragma unroll
      for (int m = 0; m < 4; m++)
        af[m] = *(const bf16x8*)(h1 + (size_t)(tb + m * 16 + l15) * H1W + kk + quad * 8);
#pragma unroll
      for (int s = 0; s < 2; s++) {
        bf16x8 bf = *(const bf16x8*)(W2 + (size_t)((wid * 2 + s) * 16 + l15) * W2S + kk + quad * 8);
#pragma unroll
        for (int m = 0; m < 4; m++)
          acc[m][s] = __builtin_amdgcn_mfma_f32_16x16x32_bf16(af[m], bf, acc[m][s], 0, 0, 0);
      }
    }
#pragma unroll
    for (int m = 0; m < 4; m++) {
#pragma unroll
      for (int s = 0; s < 2; s++) {
        int col = (wid * 2 + s) * 16 + l15;
#pragma unroll
        for (int r = 0; r < 4; r++) {
          int tok = tb + m * 16 + quad * 4 + r;
          float v = acc[m][s][r] + bias[s];
          v = v > 0.0f ? v : 0.0f;
          out[(size_t)tok * EMB + col] = v + bf2f(att[(size_t)tok * ATTW + aoff[s]]);
        }
      }
    }
  }
}

extern "C" void kernel_launch(void* const* d_in, const int* in_sizes, int n_in,
                              void* d_out, int out_size, void* d_ws, size_t ws_size,
                              hipStream_t stream) {
  const float* x         = (const float*)d_in[0];
  const float* ln1_g     = (const float*)d_in[1];
  const float* ln1_b     = (const float*)d_in[2];
  const float* acc_wqkv  = (const float*)d_in[3];
  const float* acc_bqkv  = (const float*)d_in[4];
  const float* acc_wo    = (const float*)d_in[5];
  const float* acc_bo    = (const float*)d_in[6];
  const float* gyro_wqkv = (const float*)d_in[7];
  const float* gyro_bqkv = (const float*)d_in[8];
  const float* gyro_wo   = (const float*)d_in[9];
  const float* gyro_bo   = (const float*)d_in[10];
  const float* conv_w    = (const float*)d_in[11];
  const float* ln2_g     = (const float*)d_in[12];
  const float* ln2_b     = (const float*)d_in[13];
  const float* w1        = (const float*)d_in[14];
  const float* b1        = (const float*)d_in[15];
  const float* w2        = (const float*)d_in[16];
  const float* b2        = (const float*)d_in[17];
  float* out = (float*)d_out;
  char* ws = (char*)d_ws;

  u16* qkvb = (u16*)(ws);                      // [N,288] bf16  37,748,736
  u16* tnb  = (u16*)(ws);                      // [N,192] bf16  25,165,824 (aliases dead qkvb)
  u16* attb = (u16*)(ws + 37748736);           // [N,192] bf16  25,165,824
  u16* w1b  = (u16*)(ws + 62914560);           // 147,456
  u16* w2b  = (u16*)(ws + 63062016);           // 147,456
  u16* wqp  = (u16*)(ws + 63209472);           // 36,864
  u16* wop  = (u16*)(ws + 63246336);           // 12,288
  u16* h1b  = (u16*)(ws + 63258624);           // [N,384] bf16  50,331,648 -> end 113,590,272

  pack_kernel<<<672, 256, 0, stream>>>(w1, w2, acc_wqkv, gyro_wqkv, acc_wo,
                                       gyro_wo, w1b, w2b, wqp, wop);
  ln1_qkv_conv_kernel<<<NTOK / 32, 256, 0, stream>>>(
      x, ln1_g, ln1_b, wqp, acc_bqkv, gyro_bqkv, conv_w, qkvb, attb);
  attn_kernel<<<NB * 6, 512, 0, stream>>>(qkvb, attb);
  outproj_ln2_kernel<<<NTOK / 64, 256, 0, stream>>>(
      attb, wop, acc_bo, gyro_bo, x, ln2_g, ln2_b, tnb);
  ffn1_kernel<<<256, 512, 0, stream>>>(tnb, w1b, b1, h1b);
  ffn2_kernel<<<256, 384, 0, stream>>>(h1b, w2b, b2, attb, out);
}